// Round 6
// baseline (604.407 us; speedup 1.0000x reference)
//
#include <hip/hip_runtime.h>
#include <hip/hip_cooperative_groups.h>
#include <hip/hip_bf16.h>
#include <float.h>
#include <math.h>

namespace cg = cooperative_groups;

#define NPTS 500
#define NP12 12
#define NPP  4
#define SLOPE 0.01f

__device__ __forceinline__ float lrelu(float x) { return x > 0.f ? x : SLOPE * x; }

// ---------------------------------------------------------------------------
// All device pointers in one kernarg struct (single cooperative kernel).
// ---------------------------------------------------------------------------
struct P3DParams {
    const float *img, *cloud, *img_tar, *cloud_tar, *current_feat, *target_feat;
    const float *Wc1, *bc1, *Wc2, *bc2;       // ifeat
    const float *Wp1, *bp1, *Wp2, *bp2;       // pfeat
    const float *Wfc1, *bfc1, *Wfc2, *bfc2;
    const float *Wf2, *bf2;
    const float *Wpn1, *bpn1, *Wpn2, *bpn2, *Wpn3, *bpn3;
    int *inds, *inds_self2, *inds_pp;
    float *w_ct, *w_cc, *partials;
    float *P_ct, *P_c, *F_it, *F_ic;
    float *img_diff, *cloud_diff, *spd, *sid;
    float *fuse_i, *fuse_p, *fuse_t_c, *x1, *x2;
    float *pn3part;   // 4 x 80000, aliases img_diff..fuse_p (dead by stage G)
    float *out;
};

// ---------------------------------------------------------------------------
// Stage A1: KNN task (one block-task = 4 wave-queries). Also emits softmax
// numerators e=exp(-sqrt(d2+eps)) for p<2 (bv IS the selected distance) and
// per-wave partial sums into partials[wid] (summed redundantly in stage B).
// ---------------------------------------------------------------------------
__device__ __forceinline__ void knn_task(const P3DParams& p, int task, int tid,
                                         float* sm) {
    float* c_lds  = sm;
    float* ct_lds = sm + 1504;
    for (int i = tid; i < 1500; i += 256) {
        c_lds[i]  = p.cloud[i];
        ct_lds[i] = p.cloud_tar[i];
    }
    __syncthreads();

    const int wid  = task * 4 + (tid >> 6);   // < 1500 (375 tasks)
    const int lane = tid & 63;
    const int prob = wid / NPTS;
    const int n    = wid % NPTS;

    const float* Q; const float* R; int k; int* out; float* w;
    if (prob == 0)      { Q = ct_lds; R = c_lds;  k = NP12; out = p.inds;       w = p.w_ct; }
    else if (prob == 1) { Q = ct_lds; R = ct_lds; k = NP12; out = p.inds_self2; w = p.w_cc; }
    else                { Q = c_lds;  R = ct_lds; k = NPP;  out = p.inds_pp;    w = nullptr; }

    const float qx = Q[n * 3 + 0];
    const float qy = Q[n * 3 + 1];
    const float qz = Q[n * 3 + 2];

    float d[8];
#pragma unroll
    for (int j = 0; j < 8; ++j) {
        int idx = j * 64 + lane;
        float dd = FLT_MAX;
        if (idx < NPTS) {
            float dx = qx - R[idx * 3 + 0];
            float dy = qy - R[idx * 3 + 1];
            float dz = qz - R[idx * 3 + 2];
            dd = dx * dx + dy * dy + dz * dz;
        }
        d[j] = dd;
    }

    float sum_e = 0.f;
    for (int t = 0; t < k; ++t) {
        float bv = d[0]; int bj = 0;
#pragma unroll
        for (int j = 1; j < 8; ++j) {
            if (d[j] < bv) { bv = d[j]; bj = j; }
        }
        int bidx = bj * 64 + lane;
#pragma unroll
        for (int s = 32; s >= 1; s >>= 1) {
            float ov = __shfl_xor(bv, s, 64);
            int   oi = __shfl_xor(bidx, s, 64);
            if (ov < bv || (ov == bv && oi < bidx)) { bv = ov; bidx = oi; }
        }
        if (w) {
            float e = expf(-sqrtf(bv + 1e-12f));   // all lanes identical
            sum_e += e;
            if (lane == 0) w[n * NP12 + t] = e;
        }
        if (lane == 0) out[n * k + t] = bidx;
        bool mine = (lane == (bidx & 63));
        int jj = bidx >> 6;
#pragma unroll
        for (int j = 0; j < 8; ++j) {
            if (mine && jj == j) d[j] = FLT_MAX;
        }
    }
    if (w && lane == 0) p.partials[wid] = sum_e;
}

// ---------------------------------------------------------------------------
// Stage A2: fused 2-layer conv chain task f in [0,32): chain=f>>3, colb=f&7.
// ---------------------------------------------------------------------------
__device__ __forceinline__ void featchain_task(const P3DParams& p, int f, int tid,
                                               float* sm) {
    float* xin = sm;          // 32*64
    float* mid = sm + 2048;   // 64*64

    const int chain = f >> 3;
    const int wave = __builtin_amdgcn_readfirstlane(tid >> 6);
    const int lane = tid & 63;
    const int col0 = (f & 7) * 64;

    const float *src, *W1, *B1, *W2, *B2;
    float* dst;
    int Cin; bool coord;
    switch (chain) {
        case 0: src = p.cloud_tar; W1 = p.Wp1; B1 = p.bp1; W2 = p.Wp2; B2 = p.bp2; dst = p.P_ct; Cin = 3;  coord = true;  break;
        case 1: src = p.cloud;     W1 = p.Wp1; B1 = p.bp1; W2 = p.Wp2; B2 = p.bp2; dst = p.P_c;  Cin = 3;  coord = true;  break;
        case 2: src = p.img_tar;   W1 = p.Wc1; B1 = p.bc1; W2 = p.Wc2; B2 = p.bc2; dst = p.F_it; Cin = 32; coord = false; break;
        default:src = p.img;       W1 = p.Wc1; B1 = p.bc1; W2 = p.Wc2; B2 = p.bc2; dst = p.F_ic; Cin = 32; coord = false; break;
    }

    for (int idx = tid; idx < Cin * 64; idx += 256) {
        int i = idx >> 6;
        int cl = idx & 63;
        int nn = col0 + cl;
        float v = 0.f;
        if (nn < NPTS) v = coord ? src[nn * 3 + i] : src[i * NPTS + nn];
        xin[i * 64 + cl] = v;
    }
    __syncthreads();

    {
        const int m0 = wave * 16;
        float accm[16];
#pragma unroll
        for (int r = 0; r < 16; ++r) accm[r] = B1[m0 + r];
        for (int i = 0; i < Cin; ++i) {
            float xv = xin[i * 64 + lane];
#pragma unroll
            for (int r = 0; r < 16; ++r)
                accm[r] = fmaf(W1[(m0 + r) * Cin + i], xv, accm[r]);
        }
#pragma unroll
        for (int r = 0; r < 16; ++r)
            mid[(m0 + r) * 64 + lane] = lrelu(accm[r]);
    }
    __syncthreads();

    const int nn = col0 + lane;
    for (int og = 0; og < 4; ++og) {
        const int o0 = wave * 32 + og * 8;
        float acc[8];
#pragma unroll
        for (int r = 0; r < 8; ++r) acc[r] = B2[o0 + r];
#pragma unroll 16
        for (int m = 0; m < 64; ++m) {
            float xv = mid[m * 64 + lane];
#pragma unroll
            for (int r = 0; r < 8; ++r)
                acc[r] = fmaf(W2[(o0 + r) * 64 + m], xv, acc[r]);
        }
        if (nn < NPTS) {
#pragma unroll
            for (int r = 0; r < 8; ++r)
                dst[(o0 + r) * NPTS + nn] = acc[r];
        }
    }
}

// ---------------------------------------------------------------------------
// Stage B: diff + sdiff fused, one channel per task (128 tasks). Gather
// sources staged in LDS; each block redundantly reduces the 1000 softmax
// partials (no atomics / extra grid sync).
// ---------------------------------------------------------------------------
__device__ __forceinline__ void diff_sdiff_task(const P3DParams& p, int ch, int tid,
                                                float* sm) {
    float* sFic = sm;
    float* sPc  = sm + 512;
    float* sID  = sm + 1024;
    float* sCD  = sm + 1536;
    float* red  = sm + 2048;   // 8 floats

    float l0 = 0.f, l1 = 0.f;
    for (int i = tid; i < 500; i += 256) {
        l0 += p.partials[i];
        l1 += p.partials[500 + i];
    }
#pragma unroll
    for (int s = 32; s >= 1; s >>= 1) {
        l0 += __shfl_xor(l0, s, 64);
        l1 += __shfl_xor(l1, s, 64);
    }
    if ((tid & 63) == 0) {
        red[(tid >> 6) * 2]     = l0;
        red[(tid >> 6) * 2 + 1] = l1;
    }
    for (int i = tid; i < 500; i += 256) {
        sFic[i] = p.F_ic[ch * NPTS + i];
        sPc[i]  = p.P_c[ch * NPTS + i];
    }
    __syncthreads();
    const float inv0 = 1.f / (red[0] + red[2] + red[4] + red[6]);
    const float inv1 = 1.f / (red[1] + red[3] + red[5] + red[7]);

    for (int n = tid; n < 500; n += 256) {
        float maxI = -FLT_MAX, maxP = -FLT_MAX;
#pragma unroll
        for (int j = 0; j < NP12; ++j) {
            int idx  = p.inds[n * NP12 + j];
            float wv = p.w_ct[n * NP12 + j] * inv0;
            maxI = fmaxf(maxI, sFic[idx] * wv);
            maxP = fmaxf(maxP, sPc[idx] * wv);
        }
        float idv = p.F_it[ch * NPTS + n] - maxI;
        float cdv = p.P_ct[ch * NPTS + n] - maxP;
        p.img_diff[ch * NPTS + n]   = idv;
        p.cloud_diff[ch * NPTS + n] = cdv;
        sID[n] = idv;
        sCD[n] = cdv;
    }
    __syncthreads();
    for (int n = tid; n < 500; n += 256) {
        float maxP = -FLT_MAX, maxI = -FLT_MAX;
#pragma unroll
        for (int j = 0; j < NP12; ++j) {
            int idx  = p.inds_self2[n * NP12 + j];
            float wv = p.w_cc[n * NP12 + j] * inv1;
            maxP = fmaxf(maxP, sCD[idx] * wv);
            maxI = fmaxf(maxI, sID[idx] * wv);
        }
        p.spd[ch * NPTS + n] = maxP;
        p.sid[ch * NPTS + n] = maxI;
    }
}

// ---------------------------------------------------------------------------
// GEMM core (verified r4): Y[r,n] = bias + sum_k W[r*ldW+kOffW+k]*X[k,n],
// X = concat(X1:K1, X2:K2). wave -> 2 rows x 64 cols; K chunked by 32 in LDS;
// register double-buffer for the next chunk. No lambdas (clang crash, r3).
// Over-reads <=12 floats past a row end: arena guard gaps cover it.
// ---------------------------------------------------------------------------
__device__ __forceinline__ const float* gemm_src(
        const float* __restrict__ X1, int K1, const float* __restrict__ X2,
        int k, int coloff) {
    if (k < K1) return X1 + (size_t)k * NPTS + coloff;
    return X2 + (size_t)(k - K1) * NPTS + coloff;
}

__device__ __forceinline__ void gemm_dev(
        const float* __restrict__ W, int ldW, int kOffW,
        const float* __restrict__ Bv,
        const float* __restrict__ X1, int K1,
        const float* __restrict__ X2, int K2,
        float* __restrict__ Y, int r0, int col0,
        int mode, const float* __restrict__ aux, float* Xs) {
    const int tid  = threadIdx.x;
    const int lane = tid & 63;
    const int n    = col0 + lane;
    const int srow = tid >> 3;
    const int scol = (tid & 7) * 8;
    const int coloff = col0 + scol;

    float acc0 = Bv ? Bv[r0]     : 0.f;
    float acc1 = Bv ? Bv[r0 + 1] : 0.f;

    const int nchunks = (K1 + K2) >> 5;

    const float* s = gemm_src(X1, K1, X2, srow, coloff);
    float4 ra = *(const float4*)s;
    float4 rb = *(const float4*)(s + 4);

    for (int c = 0; c < nchunks; ++c) {
        __syncthreads();
        float* dsh = &Xs[srow * 64 + scol];
        *(float4*)dsh       = ra;
        *(float4*)(dsh + 4) = rb;
        if (c + 1 < nchunks) {
            const float* sn = gemm_src(X1, K1, X2, (c + 1) * 32 + srow, coloff);
            ra = *(const float4*)sn;
            rb = *(const float4*)(sn + 4);
        }
        __syncthreads();
        const float* w0 = &W[(size_t)r0 * ldW + kOffW + c * 32];
        const float* w1 = w0 + ldW;
#pragma unroll
        for (int k = 0; k < 32; ++k) {
            float xv = Xs[k * 64 + lane];
            acc0 = fmaf(w0[k], xv, acc0);
            acc1 = fmaf(w1[k], xv, acc1);
        }
    }

    if (n < NPTS) {
        float v0 = acc0, v1 = acc1;
        if (mode == 1) { v0 = lrelu(v0); v1 = lrelu(v1); }
        else if (mode == 2) {
            v0 *= aux[r0 * NPTS + n];
            v1 *= aux[(r0 + 1) * NPTS + n];
        }
        Y[r0 * NPTS + n]       = v0;
        Y[(r0 + 1) * NPTS + n] = v1;
    }
}

// ---------------------------------------------------------------------------
// ONE cooperative kernel, grid-stride over task IDs in every stage (works for
// any grid size). __launch_bounds__(256,4) -> 4 blocks/CU co-resident
// (4 x 24.6KB LDS = 98KB < 160KB; VGPR capped at 128). Launched with
// min(1024, occupancy-query) blocks.
// ---------------------------------------------------------------------------
__global__ __launch_bounds__(256, 4) void mega_kernel(P3DParams p) {
    cg::grid_group grid = cg::this_grid();
    __shared__ __align__(16) float smem[6144];
    const int tid = threadIdx.x;
    const int bid = blockIdx.x;
    const int nb  = gridDim.x;
    const int wave = __builtin_amdgcn_readfirstlane(tid >> 6);

    // ---- A: knn (tasks 0..374) + featchain (tasks 375..406) ----
    for (int task = bid; task < 407; task += nb) {
        __syncthreads();
        if (task < 375) knn_task(p, task, tid, smem);
        else            featchain_task(p, task - 375, tid, smem);
    }
    grid.sync();

    // ---- B: diff + sdiff, one channel per task (128) ----
    for (int t = bid; t < 128; t += nb) {
        __syncthreads();
        diff_sdiff_task(p, t, tid, smem);
    }
    grid.sync();

    // ---- C: fc1 (fuse_i) + fc2 (fuse_p), 128 tasks ----
    for (int t = bid; t < 128; t += nb) {
        __syncthreads();
        const int y = t >> 3, x = t & 7;
        const int r0 = (y & 7) * 8 + wave * 2;
        if (y < 8)
            gemm_dev(p.Wfc1, 256, 0, p.bfc1, p.img_diff, 128, p.spd, 128,
                     p.fuse_i, r0, x * 64, 0, nullptr, smem);
        else
            gemm_dev(p.Wfc2, 256, 0, p.bfc2, p.cloud_diff, 128, p.sid, 128,
                     p.fuse_p, r0, x * 64, 0, nullptr, smem);
    }
    grid.sync();

    // ---- D: fuse2 (160,500), 160 tasks ----
    for (int t = bid; t < 160; t += nb) {
        __syncthreads();
        const int y = t >> 3, x = t & 7;
        gemm_dev(p.Wf2, 128, 0, p.bf2, p.fuse_p, 64, p.fuse_i, 64,
                 p.fuse_t_c, y * 8 + wave * 2, x * 64, 0, nullptr, smem);
    }
    grid.sync();

    // ---- E: pn1 (256,500), 256 tasks ----
    for (int t = bid; t < 256; t += nb) {
        __syncthreads();
        const int y = t >> 3, x = t & 7;
        gemm_dev(p.Wpn1, 160, 0, p.bpn1, p.fuse_t_c, 160, nullptr, 0,
                 p.x1, y * 8 + wave * 2, x * 64, 0, nullptr, smem);
    }
    grid.sync();

    // ---- F: pn2 (1024,500) + lrelu, 1024 tasks ----
    for (int t = bid; t < 1024; t += nb) {
        __syncthreads();
        const int y = t >> 3, x = t & 7;
        gemm_dev(p.Wpn2, 256, 0, p.bpn2, p.x1, 256, nullptr, 0,
                 p.x2, y * 8 + wave * 2, x * 64, 1, nullptr, smem);
    }
    grid.sync();

    // ---- G: pn3 split-K x4 -> partials (no bias), 640 tasks ----
    for (int t = bid; t < 640; t += nb) {
        __syncthreads();
        const int p4 = t / 160;
        const int r  = t % 160;
        const int y = r >> 3, x = r & 7;
        gemm_dev(p.Wpn3, 1024, p4 * 256, nullptr,
                 p.x2 + (size_t)p4 * 256 * NPTS, 256, nullptr, 0,
                 p.pn3part + (size_t)p4 * 80000,
                 y * 8 + wave * 2, x * 64, 0, nullptr, smem);
    }
    grid.sync();

    // ---- H: out = current_feat + mean_4( target_feat*(sum part + b_pn3) ) ----
    const float* part = p.pn3part;
    for (int gid = bid * 256 + tid; gid < 160 * NPTS; gid += nb * 256) {
        int ch = gid / NPTS;
        int n  = gid % NPTS;
        float bias = p.bpn3[ch];
        float s = 0.f;
#pragma unroll
        for (int j = 0; j < NPP; ++j) {
            int m = ch * NPTS + p.inds_pp[n * NPP + j];
            float v = bias + part[m] + part[80000 + m] + part[160000 + m] + part[240000 + m];
            s += p.target_feat[m] * v;
        }
        p.out[gid] = p.current_feat[gid] + 0.25f * s;
    }
}

// ---------------------------------------------------------------------------
extern "C" void kernel_launch(void* const* d_in, const int* in_sizes, int n_in,
                              void* d_out, int out_size, void* d_ws, size_t ws_size,
                              hipStream_t stream) {
    P3DParams prm;
    prm.img          = (const float*)d_in[0];
    prm.cloud        = (const float*)d_in[1];
    prm.img_tar      = (const float*)d_in[2];
    prm.cloud_tar    = (const float*)d_in[3];
    prm.current_feat = (const float*)d_in[4];
    prm.target_feat  = (const float*)d_in[5];
    prm.Wc1 = (const float*)d_in[6];  prm.bc1 = (const float*)d_in[7];
    prm.Wc2 = (const float*)d_in[8];  prm.bc2 = (const float*)d_in[9];
    prm.Wp1 = (const float*)d_in[10]; prm.bp1 = (const float*)d_in[11];
    prm.Wp2 = (const float*)d_in[12]; prm.bp2 = (const float*)d_in[13];
    prm.Wfc1 = (const float*)d_in[14]; prm.bfc1 = (const float*)d_in[15];
    prm.Wfc2 = (const float*)d_in[16]; prm.bfc2 = (const float*)d_in[17];
    prm.Wf2  = (const float*)d_in[18]; prm.bf2  = (const float*)d_in[19];
    prm.Wpn1 = (const float*)d_in[20]; prm.bpn1 = (const float*)d_in[21];
    prm.Wpn2 = (const float*)d_in[22]; prm.bpn2 = (const float*)d_in[23];
    prm.Wpn3 = (const float*)d_in[24]; prm.bpn3 = (const float*)d_in[25];

    // ws arena (floats); 64-float guard gaps cover GEMM staging over-reads.
    float* ws = (float*)d_ws;
    size_t off = 0;
    auto alloc = [&](size_t nfl) { float* q = ws + off; off += ((nfl + 63) & ~size_t(63)) + 64; return q; };
    prm.inds       = (int*)alloc(6000);
    prm.inds_self2 = (int*)alloc(6000);
    prm.inds_pp    = (int*)alloc(2000);
    prm.w_ct       = alloc(6000);
    prm.w_cc       = alloc(6000);
    prm.partials   = alloc(1000);
    prm.P_ct       = alloc(64000);
    prm.P_c        = alloc(64000);
    prm.F_it       = alloc(64000);
    prm.F_ic       = alloc(64000);
    prm.img_diff   = alloc(64000);
    prm.cloud_diff = alloc(64000);
    prm.spd        = alloc(64000);
    prm.sid        = alloc(64000);
    prm.fuse_i     = alloc(32000);
    prm.fuse_p     = alloc(32000);
    prm.fuse_t_c   = alloc(80000);
    prm.x1         = alloc(128000);
    prm.x2         = alloc(512000);
    prm.out        = (float*)d_out;

    // pn3 partials (4 x 80000 = 320000 fl) alias img_diff..fuse_p
    // (4*64064 + 2*32064 = 320384 fl available; all dead once stage D ran).
    prm.pn3part = prm.img_diff;

    // Grid size: min(1024, max co-resident blocks). Host-side query only —
    // graph-capture safe, deterministic across calls.
    int mb = 0;
    (void)hipOccupancyMaxActiveBlocksPerMultiprocessor(&mb, (const void*)mega_kernel, 256, 0);
    int nblk = 1024;
    if (mb > 0 && mb * 256 < nblk) nblk = mb * 256;

    void* args[] = { &prm };
    hipLaunchCooperativeKernel((void*)mega_kernel, dim3(nblk), dim3(256),
                               args, 0, stream);
}

// Round 7
// 457.443 us; speedup vs baseline: 1.3213x; 1.3213x over previous
//
#include <hip/hip_runtime.h>
#include <hip/hip_cooperative_groups.h>
#include <hip/hip_bf16.h>
#include <float.h>
#include <math.h>

namespace cg = cooperative_groups;

#define NPTS 500
#define NP12 12
#define NPP  4
#define SLOPE 0.01f

__device__ __forceinline__ float lrelu(float x) { return x > 0.f ? x : SLOPE * x; }

// ---------------------------------------------------------------------------
// All device pointers in one kernarg struct (single cooperative kernel).
// ---------------------------------------------------------------------------
struct P3DParams {
    const float *img, *cloud, *img_tar, *cloud_tar, *current_feat, *target_feat;
    const float *Wc1, *bc1, *Wc2, *bc2;       // ifeat
    const float *Wp1, *bp1, *Wp2, *bp2;       // pfeat
    const float *Wfc1, *bfc1, *Wfc2, *bfc2;
    const float *Wf2, *bf2;
    const float *Wpn1, *bpn1, *Wpn2, *bpn2, *Wpn3, *bpn3;
    int *inds, *inds_self2, *inds_pp;
    float *w_ct, *w_cc, *partials;
    float *P_ct, *P_c, *F_it, *F_ic;
    float *img_diff, *cloud_diff, *spd, *sid;
    float *fuse_i, *fuse_p, *fuse_t_c, *x1, *x2;
    float *pn3part;   // 4 x 80000, aliases img_diff..fuse_p (dead by stage G)
    float *out;
};

// ---------------------------------------------------------------------------
// Stage A1: KNN task (one block-task = 4 wave-queries). Also emits softmax
// numerators e=exp(-sqrt(d2+eps)) for p<2 (bv IS the selected distance) and
// per-wave partial sums into partials[wid] (summed redundantly in stage B).
// ---------------------------------------------------------------------------
__device__ __forceinline__ void knn_task(const P3DParams& p, int task, int tid,
                                         float* sm) {
    float* c_lds  = sm;
    float* ct_lds = sm + 1504;
    for (int i = tid; i < 1500; i += 256) {
        c_lds[i]  = p.cloud[i];
        ct_lds[i] = p.cloud_tar[i];
    }
    __syncthreads();

    const int wid  = task * 4 + (tid >> 6);   // < 1500 (375 tasks)
    const int lane = tid & 63;
    const int prob = wid / NPTS;
    const int n    = wid % NPTS;

    const float* Q; const float* R; int k; int* out; float* w;
    if (prob == 0)      { Q = ct_lds; R = c_lds;  k = NP12; out = p.inds;       w = p.w_ct; }
    else if (prob == 1) { Q = ct_lds; R = ct_lds; k = NP12; out = p.inds_self2; w = p.w_cc; }
    else                { Q = c_lds;  R = ct_lds; k = NPP;  out = p.inds_pp;    w = nullptr; }

    const float qx = Q[n * 3 + 0];
    const float qy = Q[n * 3 + 1];
    const float qz = Q[n * 3 + 2];

    float d[8];
#pragma unroll
    for (int j = 0; j < 8; ++j) {
        int idx = j * 64 + lane;
        float dd = FLT_MAX;
        if (idx < NPTS) {
            float dx = qx - R[idx * 3 + 0];
            float dy = qy - R[idx * 3 + 1];
            float dz = qz - R[idx * 3 + 2];
            dd = dx * dx + dy * dy + dz * dz;
        }
        d[j] = dd;
    }

    float sum_e = 0.f;
    for (int t = 0; t < k; ++t) {
        float bv = d[0]; int bj = 0;
#pragma unroll
        for (int j = 1; j < 8; ++j) {
            if (d[j] < bv) { bv = d[j]; bj = j; }
        }
        int bidx = bj * 64 + lane;
#pragma unroll
        for (int s = 32; s >= 1; s >>= 1) {
            float ov = __shfl_xor(bv, s, 64);
            int   oi = __shfl_xor(bidx, s, 64);
            if (ov < bv || (ov == bv && oi < bidx)) { bv = ov; bidx = oi; }
        }
        if (w) {
            float e = expf(-sqrtf(bv + 1e-12f));   // all lanes identical
            sum_e += e;
            if (lane == 0) w[n * NP12 + t] = e;
        }
        if (lane == 0) out[n * k + t] = bidx;
        bool mine = (lane == (bidx & 63));
        int jj = bidx >> 6;
#pragma unroll
        for (int j = 0; j < 8; ++j) {
            if (mine && jj == j) d[j] = FLT_MAX;
        }
    }
    if (w && lane == 0) p.partials[wid] = sum_e;
}

// ---------------------------------------------------------------------------
// Stage A2: fused 2-layer conv chain task f in [0,32): chain=f>>3, colb=f&7.
// ---------------------------------------------------------------------------
__device__ __forceinline__ void featchain_task(const P3DParams& p, int f, int tid,
                                               float* sm) {
    float* xin = sm;          // 32*64
    float* mid = sm + 2048;   // 64*64

    const int chain = f >> 3;
    const int wave = __builtin_amdgcn_readfirstlane(tid >> 6);
    const int lane = tid & 63;
    const int col0 = (f & 7) * 64;

    const float *src, *W1, *B1, *W2, *B2;
    float* dst;
    int Cin; bool coord;
    switch (chain) {
        case 0: src = p.cloud_tar; W1 = p.Wp1; B1 = p.bp1; W2 = p.Wp2; B2 = p.bp2; dst = p.P_ct; Cin = 3;  coord = true;  break;
        case 1: src = p.cloud;     W1 = p.Wp1; B1 = p.bp1; W2 = p.Wp2; B2 = p.bp2; dst = p.P_c;  Cin = 3;  coord = true;  break;
        case 2: src = p.img_tar;   W1 = p.Wc1; B1 = p.bc1; W2 = p.Wc2; B2 = p.bc2; dst = p.F_it; Cin = 32; coord = false; break;
        default:src = p.img;       W1 = p.Wc1; B1 = p.bc1; W2 = p.Wc2; B2 = p.bc2; dst = p.F_ic; Cin = 32; coord = false; break;
    }

    for (int idx = tid; idx < Cin * 64; idx += 256) {
        int i = idx >> 6;
        int cl = idx & 63;
        int nn = col0 + cl;
        float v = 0.f;
        if (nn < NPTS) v = coord ? src[nn * 3 + i] : src[i * NPTS + nn];
        xin[i * 64 + cl] = v;
    }
    __syncthreads();

    {
        const int m0 = wave * 16;
        float accm[16];
#pragma unroll
        for (int r = 0; r < 16; ++r) accm[r] = B1[m0 + r];
        for (int i = 0; i < Cin; ++i) {
            float xv = xin[i * 64 + lane];
#pragma unroll
            for (int r = 0; r < 16; ++r)
                accm[r] = fmaf(W1[(m0 + r) * Cin + i], xv, accm[r]);
        }
#pragma unroll
        for (int r = 0; r < 16; ++r)
            mid[(m0 + r) * 64 + lane] = lrelu(accm[r]);
    }
    __syncthreads();

    const int nn = col0 + lane;
    for (int og = 0; og < 4; ++og) {
        const int o0 = wave * 32 + og * 8;
        float acc[8];
#pragma unroll
        for (int r = 0; r < 8; ++r) acc[r] = B2[o0 + r];
#pragma unroll 16
        for (int m = 0; m < 64; ++m) {
            float xv = mid[m * 64 + lane];
#pragma unroll
            for (int r = 0; r < 8; ++r)
                acc[r] = fmaf(W2[(o0 + r) * 64 + m], xv, acc[r]);
        }
        if (nn < NPTS) {
#pragma unroll
            for (int r = 0; r < 8; ++r)
                dst[(o0 + r) * NPTS + nn] = acc[r];
        }
    }
}

// ---------------------------------------------------------------------------
// Stage B: diff + sdiff fused, one channel per task (128 tasks). Gather
// sources staged in LDS; each block redundantly reduces the 1000 softmax
// partials (no atomics / extra grid sync).
// ---------------------------------------------------------------------------
__device__ __forceinline__ void diff_sdiff_task(const P3DParams& p, int ch, int tid,
                                                float* sm) {
    float* sFic = sm;
    float* sPc  = sm + 512;
    float* sID  = sm + 1024;
    float* sCD  = sm + 1536;
    float* red  = sm + 2048;   // 8 floats

    float l0 = 0.f, l1 = 0.f;
    for (int i = tid; i < 500; i += 256) {
        l0 += p.partials[i];
        l1 += p.partials[500 + i];
    }
#pragma unroll
    for (int s = 32; s >= 1; s >>= 1) {
        l0 += __shfl_xor(l0, s, 64);
        l1 += __shfl_xor(l1, s, 64);
    }
    if ((tid & 63) == 0) {
        red[(tid >> 6) * 2]     = l0;
        red[(tid >> 6) * 2 + 1] = l1;
    }
    for (int i = tid; i < 500; i += 256) {
        sFic[i] = p.F_ic[ch * NPTS + i];
        sPc[i]  = p.P_c[ch * NPTS + i];
    }
    __syncthreads();
    const float inv0 = 1.f / (red[0] + red[2] + red[4] + red[6]);
    const float inv1 = 1.f / (red[1] + red[3] + red[5] + red[7]);

    for (int n = tid; n < 500; n += 256) {
        float maxI = -FLT_MAX, maxP = -FLT_MAX;
#pragma unroll
        for (int j = 0; j < NP12; ++j) {
            int idx  = p.inds[n * NP12 + j];
            float wv = p.w_ct[n * NP12 + j] * inv0;
            maxI = fmaxf(maxI, sFic[idx] * wv);
            maxP = fmaxf(maxP, sPc[idx] * wv);
        }
        float idv = p.F_it[ch * NPTS + n] - maxI;
        float cdv = p.P_ct[ch * NPTS + n] - maxP;
        p.img_diff[ch * NPTS + n]   = idv;
        p.cloud_diff[ch * NPTS + n] = cdv;
        sID[n] = idv;
        sCD[n] = cdv;
    }
    __syncthreads();
    for (int n = tid; n < 500; n += 256) {
        float maxP = -FLT_MAX, maxI = -FLT_MAX;
#pragma unroll
        for (int j = 0; j < NP12; ++j) {
            int idx  = p.inds_self2[n * NP12 + j];
            float wv = p.w_cc[n * NP12 + j] * inv1;
            maxP = fmaxf(maxP, sCD[idx] * wv);
            maxI = fmaxf(maxI, sID[idx] * wv);
        }
        p.spd[ch * NPTS + n] = maxP;
        p.sid[ch * NPTS + n] = maxI;
    }
}

// ---------------------------------------------------------------------------
// GEMM core (verified r4): Y[r,n] = bias + sum_k W[r*ldW+kOffW+k]*X[k,n],
// X = concat(X1:K1, X2:K2). wave -> 2 rows x 64 cols; K chunked by 32 in LDS;
// register double-buffer for the next chunk. No lambdas (clang crash, r3).
// Over-reads <=12 floats past a row end: arena guard gaps cover it.
// ---------------------------------------------------------------------------
__device__ __forceinline__ const float* gemm_src(
        const float* __restrict__ X1, int K1, const float* __restrict__ X2,
        int k, int coloff) {
    if (k < K1) return X1 + (size_t)k * NPTS + coloff;
    return X2 + (size_t)(k - K1) * NPTS + coloff;
}

__device__ __forceinline__ void gemm_dev(
        const float* __restrict__ W, int ldW, int kOffW,
        const float* __restrict__ Bv,
        const float* __restrict__ X1, int K1,
        const float* __restrict__ X2, int K2,
        float* __restrict__ Y, int r0, int col0,
        int mode, const float* __restrict__ aux, float* Xs) {
    const int tid  = threadIdx.x;
    const int lane = tid & 63;
    const int n    = col0 + lane;
    const int srow = tid >> 3;
    const int scol = (tid & 7) * 8;
    const int coloff = col0 + scol;

    float acc0 = Bv ? Bv[r0]     : 0.f;
    float acc1 = Bv ? Bv[r0 + 1] : 0.f;

    const int nchunks = (K1 + K2) >> 5;

    const float* s = gemm_src(X1, K1, X2, srow, coloff);
    float4 ra = *(const float4*)s;
    float4 rb = *(const float4*)(s + 4);

    for (int c = 0; c < nchunks; ++c) {
        __syncthreads();
        float* dsh = &Xs[srow * 64 + scol];
        *(float4*)dsh       = ra;
        *(float4*)(dsh + 4) = rb;
        if (c + 1 < nchunks) {
            const float* sn = gemm_src(X1, K1, X2, (c + 1) * 32 + srow, coloff);
            ra = *(const float4*)sn;
            rb = *(const float4*)(sn + 4);
        }
        __syncthreads();
        const float* w0 = &W[(size_t)r0 * ldW + kOffW + c * 32];
        const float* w1 = w0 + ldW;
#pragma unroll
        for (int k = 0; k < 32; ++k) {
            float xv = Xs[k * 64 + lane];
            acc0 = fmaf(w0[k], xv, acc0);
            acc1 = fmaf(w1[k], xv, acc1);
        }
    }

    if (n < NPTS) {
        float v0 = acc0, v1 = acc1;
        if (mode == 1) { v0 = lrelu(v0); v1 = lrelu(v1); }
        else if (mode == 2) {
            v0 *= aux[r0 * NPTS + n];
            v1 *= aux[(r0 + 1) * NPTS + n];
        }
        Y[r0 * NPTS + n]       = v0;
        Y[(r0 + 1) * NPTS + n] = v1;
    }
}

// ---------------------------------------------------------------------------
// ONE cooperative kernel, grid-stride over task IDs in every stage.
// __launch_bounds__(256) ONLY — r6's (256,4) min-wave clause capped VGPR at
// 64 and spilled the GEMM core to scratch (WRITE_SIZE 6.2->20.7 MB, 2.6x
// slower). At the natural ~88 VGPR the HW wave budget already gives
// 4 blocks/CU (16 waves/CU), so the occupancy query still yields ~1024
// blocks — same residency, no spill.
// ---------------------------------------------------------------------------
__global__ __launch_bounds__(256) void mega_kernel(P3DParams p) {
    cg::grid_group grid = cg::this_grid();
    __shared__ __align__(16) float smem[6144];
    const int tid = threadIdx.x;
    const int bid = blockIdx.x;
    const int nb  = gridDim.x;
    const int wave = __builtin_amdgcn_readfirstlane(tid >> 6);

    // ---- A: knn (tasks 0..374) + featchain (tasks 375..406) ----
    for (int task = bid; task < 407; task += nb) {
        __syncthreads();
        if (task < 375) knn_task(p, task, tid, smem);
        else            featchain_task(p, task - 375, tid, smem);
    }
    grid.sync();

    // ---- B: diff + sdiff, one channel per task (128) ----
    for (int t = bid; t < 128; t += nb) {
        __syncthreads();
        diff_sdiff_task(p, t, tid, smem);
    }
    grid.sync();

    // ---- C: fc1 (fuse_i) + fc2 (fuse_p), 128 tasks ----
    for (int t = bid; t < 128; t += nb) {
        __syncthreads();
        const int y = t >> 3, x = t & 7;
        const int r0 = (y & 7) * 8 + wave * 2;
        if (y < 8)
            gemm_dev(p.Wfc1, 256, 0, p.bfc1, p.img_diff, 128, p.spd, 128,
                     p.fuse_i, r0, x * 64, 0, nullptr, smem);
        else
            gemm_dev(p.Wfc2, 256, 0, p.bfc2, p.cloud_diff, 128, p.sid, 128,
                     p.fuse_p, r0, x * 64, 0, nullptr, smem);
    }
    grid.sync();

    // ---- D: fuse2 (160,500), 160 tasks ----
    for (int t = bid; t < 160; t += nb) {
        __syncthreads();
        const int y = t >> 3, x = t & 7;
        gemm_dev(p.Wf2, 128, 0, p.bf2, p.fuse_p, 64, p.fuse_i, 64,
                 p.fuse_t_c, y * 8 + wave * 2, x * 64, 0, nullptr, smem);
    }
    grid.sync();

    // ---- E: pn1 (256,500), 256 tasks ----
    for (int t = bid; t < 256; t += nb) {
        __syncthreads();
        const int y = t >> 3, x = t & 7;
        gemm_dev(p.Wpn1, 160, 0, p.bpn1, p.fuse_t_c, 160, nullptr, 0,
                 p.x1, y * 8 + wave * 2, x * 64, 0, nullptr, smem);
    }
    grid.sync();

    // ---- F: pn2 (1024,500) + lrelu, 1024 tasks ----
    for (int t = bid; t < 1024; t += nb) {
        __syncthreads();
        const int y = t >> 3, x = t & 7;
        gemm_dev(p.Wpn2, 256, 0, p.bpn2, p.x1, 256, nullptr, 0,
                 p.x2, y * 8 + wave * 2, x * 64, 1, nullptr, smem);
    }
    grid.sync();

    // ---- G: pn3 split-K x4 -> partials (no bias), 640 tasks ----
    for (int t = bid; t < 640; t += nb) {
        __syncthreads();
        const int p4 = t / 160;
        const int r  = t % 160;
        const int y = r >> 3, x = r & 7;
        gemm_dev(p.Wpn3, 1024, p4 * 256, nullptr,
                 p.x2 + (size_t)p4 * 256 * NPTS, 256, nullptr, 0,
                 p.pn3part + (size_t)p4 * 80000,
                 y * 8 + wave * 2, x * 64, 0, nullptr, smem);
    }
    grid.sync();

    // ---- H: out = current_feat + mean_4( target_feat*(sum part + b_pn3) ) ----
    const float* part = p.pn3part;
    for (int gid = bid * 256 + tid; gid < 160 * NPTS; gid += nb * 256) {
        int ch = gid / NPTS;
        int n  = gid % NPTS;
        float bias = p.bpn3[ch];
        float s = 0.f;
#pragma unroll
        for (int j = 0; j < NPP; ++j) {
            int m = ch * NPTS + p.inds_pp[n * NPP + j];
            float v = bias + part[m] + part[80000 + m] + part[160000 + m] + part[240000 + m];
            s += p.target_feat[m] * v;
        }
        p.out[gid] = p.current_feat[gid] + 0.25f * s;
    }
}

// ---------------------------------------------------------------------------
extern "C" void kernel_launch(void* const* d_in, const int* in_sizes, int n_in,
                              void* d_out, int out_size, void* d_ws, size_t ws_size,
                              hipStream_t stream) {
    P3DParams prm;
    prm.img          = (const float*)d_in[0];
    prm.cloud        = (const float*)d_in[1];
    prm.img_tar      = (const float*)d_in[2];
    prm.cloud_tar    = (const float*)d_in[3];
    prm.current_feat = (const float*)d_in[4];
    prm.target_feat  = (const float*)d_in[5];
    prm.Wc1 = (const float*)d_in[6];  prm.bc1 = (const float*)d_in[7];
    prm.Wc2 = (const float*)d_in[8];  prm.bc2 = (const float*)d_in[9];
    prm.Wp1 = (const float*)d_in[10]; prm.bp1 = (const float*)d_in[11];
    prm.Wp2 = (const float*)d_in[12]; prm.bp2 = (const float*)d_in[13];
    prm.Wfc1 = (const float*)d_in[14]; prm.bfc1 = (const float*)d_in[15];
    prm.Wfc2 = (const float*)d_in[16]; prm.bfc2 = (const float*)d_in[17];
    prm.Wf2  = (const float*)d_in[18]; prm.bf2  = (const float*)d_in[19];
    prm.Wpn1 = (const float*)d_in[20]; prm.bpn1 = (const float*)d_in[21];
    prm.Wpn2 = (const float*)d_in[22]; prm.bpn2 = (const float*)d_in[23];
    prm.Wpn3 = (const float*)d_in[24]; prm.bpn3 = (const float*)d_in[25];

    // ws arena (floats); 64-float guard gaps cover GEMM staging over-reads.
    float* ws = (float*)d_ws;
    size_t off = 0;
    auto alloc = [&](size_t nfl) { float* q = ws + off; off += ((nfl + 63) & ~size_t(63)) + 64; return q; };
    prm.inds       = (int*)alloc(6000);
    prm.inds_self2 = (int*)alloc(6000);
    prm.inds_pp    = (int*)alloc(2000);
    prm.w_ct       = alloc(6000);
    prm.w_cc       = alloc(6000);
    prm.partials   = alloc(1000);
    prm.P_ct       = alloc(64000);
    prm.P_c        = alloc(64000);
    prm.F_it       = alloc(64000);
    prm.F_ic       = alloc(64000);
    prm.img_diff   = alloc(64000);
    prm.cloud_diff = alloc(64000);
    prm.spd        = alloc(64000);
    prm.sid        = alloc(64000);
    prm.fuse_i     = alloc(32000);
    prm.fuse_p     = alloc(32000);
    prm.fuse_t_c   = alloc(80000);
    prm.x1         = alloc(128000);
    prm.x2         = alloc(512000);
    prm.out        = (float*)d_out;

    // pn3 partials (4 x 80000 = 320000 fl) alias img_diff..fuse_p
    // (4*64064 + 2*32064 = 320384 fl available; all dead once stage D ran).
    prm.pn3part = prm.img_diff;

    // Grid size: min(1024, max co-resident blocks). Host-side query only —
    // graph-capture safe, deterministic across calls.
    int mb = 0;
    (void)hipOccupancyMaxActiveBlocksPerMultiprocessor(&mb, (const void*)mega_kernel, 256, 0);
    int nblk = 1024;
    if (mb > 0 && mb * 256 < nblk) nblk = mb * 256;

    void* args[] = { &prm };
    hipLaunchCooperativeKernel((void*)mega_kernel, dim3(nblk), dim3(256),
                               args, 0, stream);
}

// Round 8
// 209.903 us; speedup vs baseline: 2.8795x; 2.1793x over previous
//
#include <hip/hip_runtime.h>
#include <hip/hip_bf16.h>
#include <float.h>
#include <math.h>

#define NPTS 500
#define NP12 12
#define NPP  4
#define SLOPE 0.01f

__device__ __forceinline__ float lrelu(float x) { return x > 0.f ? x : SLOPE * x; }

// ---------------------------------------------------------------------------
// K0: weight composition (weights only, no data deps).
//  Wcomb2[1024][160] = Wpn2(1024x256) @ Wpn1(256x160)
//  bcomb2[1024]      = bpn2 + Wpn2 @ bpn1
//  Wcomb1[160][512]  = [ Wf2[:, :64]@Wfc2 (160x256) | Wf2[:,64:]@Wfc1 (160x256) ]
//  bcomb1[160]       = bf2 + Wf2[:, :64]@bfc2 + Wf2[:,64:]@bfc1
// Valid because pn1 and fc1/fc2 have NO activation before the next conv.
// ---------------------------------------------------------------------------
__global__ __launch_bounds__(256) void compose_kernel(
        const float* __restrict__ Wpn1, const float* __restrict__ bpn1,
        const float* __restrict__ Wpn2, const float* __restrict__ bpn2,
        const float* __restrict__ Wfc1, const float* __restrict__ bfc1,
        const float* __restrict__ Wfc2, const float* __restrict__ bfc2,
        const float* __restrict__ Wf2,  const float* __restrict__ bf2,
        float* __restrict__ Wcomb2, float* __restrict__ bcomb2,
        float* __restrict__ Wcomb1, float* __restrict__ bcomb1) {
    int e = blockIdx.x * 256 + threadIdx.x;
    if (e < 163840) {                       // Wcomb2
        int o = e / 160, j = e % 160;
        float acc = 0.f;
        for (int k = 0; k < 256; ++k)
            acc = fmaf(Wpn2[o * 256 + k], Wpn1[k * 160 + j], acc);
        Wcomb2[e] = acc;
        return;
    }
    e -= 163840;
    if (e < 81920) {                        // Wcomb1
        int o = e / 512, c = e % 512;
        float acc = 0.f;
        if (c < 256) {
            for (int m = 0; m < 64; ++m)
                acc = fmaf(Wf2[o * 128 + m], Wfc2[m * 256 + c], acc);
        } else {
            int cc = c - 256;
            for (int m = 0; m < 64; ++m)
                acc = fmaf(Wf2[o * 128 + 64 + m], Wfc1[m * 256 + cc], acc);
        }
        Wcomb1[o * 512 + c] = acc;
        return;
    }
    e -= 81920;
    if (e < 1024) {                         // bcomb2
        float acc = bpn2[e];
        for (int k = 0; k < 256; ++k)
            acc = fmaf(Wpn2[e * 256 + k], bpn1[k], acc);
        bcomb2[e] = acc;
        return;
    }
    e -= 1024;
    if (e < 160) {                          // bcomb1
        float acc = bf2[e];
        for (int m = 0; m < 64; ++m) {
            acc = fmaf(Wf2[e * 128 + m],      bfc2[m], acc);
            acc = fmaf(Wf2[e * 128 + 64 + m], bfc1[m], acc);
        }
        bcomb1[e] = acc;
    }
}

// ---------------------------------------------------------------------------
// K1: knn (block-tasks 0..374) + featchain (375..406), 407 blocks x 256.
// knn also emits softmax numerators exp(-sqrt(d2+eps)) (bv IS the selected
// distance) and per-query partial sums into partials[] (reduced in K2).
// ---------------------------------------------------------------------------
__global__ __launch_bounds__(256) void knnfeat_kernel(
        const float* __restrict__ cloud, const float* __restrict__ cloud_tar,
        const float* __restrict__ img, const float* __restrict__ img_tar,
        const float* __restrict__ Wp1, const float* __restrict__ bp1,
        const float* __restrict__ Wp2, const float* __restrict__ bp2,
        const float* __restrict__ Wi1, const float* __restrict__ bi1,
        const float* __restrict__ Wi2, const float* __restrict__ bi2,
        int* __restrict__ inds, int* __restrict__ inds_self2, int* __restrict__ inds_pp,
        float* __restrict__ w_ct, float* __restrict__ w_cc, float* __restrict__ partials,
        float* __restrict__ P_ct, float* __restrict__ P_c,
        float* __restrict__ F_it, float* __restrict__ F_ic) {
    __shared__ __align__(16) float sm[6144];
    const int tid = threadIdx.x;
    const int bid = blockIdx.x;

    if (bid < 375) {
        // ---------------- knn task ----------------
        float* c_lds  = sm;
        float* ct_lds = sm + 1504;
        for (int i = tid; i < 1500; i += 256) {
            c_lds[i]  = cloud[i];
            ct_lds[i] = cloud_tar[i];
        }
        __syncthreads();

        const int wid  = bid * 4 + (tid >> 6);   // < 1500
        const int lane = tid & 63;
        const int prob = wid / NPTS;
        const int n    = wid % NPTS;

        const float* Q; const float* R; int k; int* out; float* w;
        if (prob == 0)      { Q = ct_lds; R = c_lds;  k = NP12; out = inds;       w = w_ct; }
        else if (prob == 1) { Q = ct_lds; R = ct_lds; k = NP12; out = inds_self2; w = w_cc; }
        else                { Q = c_lds;  R = ct_lds; k = NPP;  out = inds_pp;    w = nullptr; }

        const float qx = Q[n * 3 + 0];
        const float qy = Q[n * 3 + 1];
        const float qz = Q[n * 3 + 2];

        float d[8];
#pragma unroll
        for (int j = 0; j < 8; ++j) {
            int idx = j * 64 + lane;
            float dd = FLT_MAX;
            if (idx < NPTS) {
                float dx = qx - R[idx * 3 + 0];
                float dy = qy - R[idx * 3 + 1];
                float dz = qz - R[idx * 3 + 2];
                dd = dx * dx + dy * dy + dz * dz;
            }
            d[j] = dd;
        }

        float sum_e = 0.f;
        for (int t = 0; t < k; ++t) {
            float bv = d[0]; int bj = 0;
#pragma unroll
            for (int j = 1; j < 8; ++j) {
                if (d[j] < bv) { bv = d[j]; bj = j; }
            }
            int bidx = bj * 64 + lane;
#pragma unroll
            for (int s = 32; s >= 1; s >>= 1) {
                float ov = __shfl_xor(bv, s, 64);
                int   oi = __shfl_xor(bidx, s, 64);
                if (ov < bv || (ov == bv && oi < bidx)) { bv = ov; bidx = oi; }
            }
            if (w) {
                float e = expf(-sqrtf(bv + 1e-12f));
                sum_e += e;
                if (lane == 0) w[n * NP12 + t] = e;
            }
            if (lane == 0) out[n * k + t] = bidx;
            bool mine = (lane == (bidx & 63));
            int jj = bidx >> 6;
#pragma unroll
            for (int j = 0; j < 8; ++j) {
                if (mine && jj == j) d[j] = FLT_MAX;
            }
        }
        if (w && lane == 0) partials[wid] = sum_e;
        return;
    }

    // ---------------- featchain task ----------------
    const int f = bid - 375;                 // 0..31
    float* xin = sm;                         // 32*64
    float* mid = sm + 2048;                  // 64*64
    const int chain = f >> 3;
    const int wave = __builtin_amdgcn_readfirstlane(tid >> 6);
    const int lane = tid & 63;
    const int col0 = (f & 7) * 64;

    const float *src, *W1, *B1, *W2, *B2;
    float* dst;
    int Cin; bool coord;
    switch (chain) {
        case 0: src = cloud_tar; W1 = Wp1; B1 = bp1; W2 = Wp2; B2 = bp2; dst = P_ct; Cin = 3;  coord = true;  break;
        case 1: src = cloud;     W1 = Wp1; B1 = bp1; W2 = Wp2; B2 = bp2; dst = P_c;  Cin = 3;  coord = true;  break;
        case 2: src = img_tar;   W1 = Wi1; B1 = bi1; W2 = Wi2; B2 = bi2; dst = F_it; Cin = 32; coord = false; break;
        default:src = img;       W1 = Wi1; B1 = bi1; W2 = Wi2; B2 = bi2; dst = F_ic; Cin = 32; coord = false; break;
    }

    for (int idx = tid; idx < Cin * 64; idx += 256) {
        int i = idx >> 6;
        int cl = idx & 63;
        int nn = col0 + cl;
        float v = 0.f;
        if (nn < NPTS) v = coord ? src[nn * 3 + i] : src[i * NPTS + nn];
        xin[i * 64 + cl] = v;
    }
    __syncthreads();

    {
        const int m0 = wave * 16;
        float accm[16];
#pragma unroll
        for (int r = 0; r < 16; ++r) accm[r] = B1[m0 + r];
        for (int i = 0; i < Cin; ++i) {
            float xv = xin[i * 64 + lane];
#pragma unroll
            for (int r = 0; r < 16; ++r)
                accm[r] = fmaf(W1[(m0 + r) * Cin + i], xv, accm[r]);
        }
#pragma unroll
        for (int r = 0; r < 16; ++r)
            mid[(m0 + r) * 64 + lane] = lrelu(accm[r]);
    }
    __syncthreads();

    const int nn = col0 + lane;
    for (int og = 0; og < 4; ++og) {
        const int o0 = wave * 32 + og * 8;
        float acc[8];
#pragma unroll
        for (int r = 0; r < 8; ++r) acc[r] = B2[o0 + r];
#pragma unroll 16
        for (int m = 0; m < 64; ++m) {
            float xv = mid[m * 64 + lane];
#pragma unroll
            for (int r = 0; r < 8; ++r)
                acc[r] = fmaf(W2[(o0 + r) * 64 + m], xv, acc[r]);
        }
        if (nn < NPTS) {
#pragma unroll
            for (int r = 0; r < 8; ++r)
                dst[(o0 + r) * NPTS + nn] = acc[r];
        }
    }
}

// ---------------------------------------------------------------------------
// K2: diff + sdiff fused, one channel per block (128 blocks). Gather sources
// staged in LDS; each block redundantly reduces the 1000 softmax partials.
// Writes into dcat, the contiguous 512x500 matrix [cd; sid; id; spd] that
// K3 consumes directly (row k at dcat + k*500).
// ---------------------------------------------------------------------------
__global__ __launch_bounds__(256) void diffsdiff_kernel(
        const float* __restrict__ F_it, const float* __restrict__ F_ic,
        const float* __restrict__ P_ct, const float* __restrict__ P_c,
        const int* __restrict__ inds, const int* __restrict__ inds_self2,
        const float* __restrict__ w_ct, const float* __restrict__ w_cc,
        const float* __restrict__ partials,
        float* __restrict__ dcat) {
    __shared__ __align__(16) float sm[2056];
    float* sFic = sm;
    float* sPc  = sm + 512;
    float* sID  = sm + 1024;
    float* sCD  = sm + 1536;
    float* red  = sm + 2048;   // 8 floats
    const int tid = threadIdx.x;
    const int ch  = blockIdx.x;

    float l0 = 0.f, l1 = 0.f;
    for (int i = tid; i < 500; i += 256) {
        l0 += partials[i];
        l1 += partials[500 + i];
    }
#pragma unroll
    for (int s = 32; s >= 1; s >>= 1) {
        l0 += __shfl_xor(l0, s, 64);
        l1 += __shfl_xor(l1, s, 64);
    }
    if ((tid & 63) == 0) {
        red[(tid >> 6) * 2]     = l0;
        red[(tid >> 6) * 2 + 1] = l1;
    }
    for (int i = tid; i < 500; i += 256) {
        sFic[i] = F_ic[ch * NPTS + i];
        sPc[i]  = P_c[ch * NPTS + i];
    }
    __syncthreads();
    const float inv0 = 1.f / (red[0] + red[2] + red[4] + red[6]);
    const float inv1 = 1.f / (red[1] + red[3] + red[5] + red[7]);

    float* cd_row  = dcat + (size_t)ch * 500;            // rows   0..127
    float* sid_row = dcat + (size_t)(128 + ch) * 500;    // rows 128..255
    float* id_row  = dcat + (size_t)(256 + ch) * 500;    // rows 256..383
    float* spd_row = dcat + (size_t)(384 + ch) * 500;    // rows 384..511

    for (int n = tid; n < 500; n += 256) {
        float maxI = -FLT_MAX, maxP = -FLT_MAX;
#pragma unroll
        for (int j = 0; j < NP12; ++j) {
            int idx  = inds[n * NP12 + j];
            float wv = w_ct[n * NP12 + j] * inv0;
            maxI = fmaxf(maxI, sFic[idx] * wv);
            maxP = fmaxf(maxP, sPc[idx] * wv);
        }
        float idv = F_it[ch * NPTS + n] - maxI;
        float cdv = P_ct[ch * NPTS + n] - maxP;
        id_row[n] = idv;
        cd_row[n] = cdv;
        sID[n] = idv;
        sCD[n] = cdv;
    }
    __syncthreads();
    for (int n = tid; n < 500; n += 256) {
        float maxP = -FLT_MAX, maxI = -FLT_MAX;
#pragma unroll
        for (int j = 0; j < NP12; ++j) {
            int idx  = inds_self2[n * NP12 + j];
            float wv = w_cc[n * NP12 + j] * inv1;
            maxP = fmaxf(maxP, sCD[idx] * wv);
            maxI = fmaxf(maxI, sID[idx] * wv);
        }
        spd_row[n] = maxP;
        sid_row[n] = maxI;
    }
}

// ---------------------------------------------------------------------------
// GEMM core (verified r4): Y[r,n] = bias + sum_k W[r*ldW+kOffW+k]*X[k,n].
// wave -> 2 rows x 64 cols; K chunked by 32 in LDS; register double-buffer.
// No lambdas (clang crash, r3). Over-reads <=12 floats past last row end:
// ws guard gaps cover it.
// ---------------------------------------------------------------------------
__device__ __forceinline__ void gemm_dev(
        const float* __restrict__ W, int ldW, int kOffW,
        const float* __restrict__ Bv,
        const float* __restrict__ X, int K,
        float* __restrict__ Y, int r0, int col0,
        int mode, const float* __restrict__ aux, float* Xs) {
    const int tid  = threadIdx.x;
    const int lane = tid & 63;
    const int n    = col0 + lane;
    const int srow = tid >> 3;
    const int scol = (tid & 7) * 8;
    const int coloff = col0 + scol;

    float acc0 = Bv ? Bv[r0]     : 0.f;
    float acc1 = Bv ? Bv[r0 + 1] : 0.f;

    const int nchunks = K >> 5;

    const float* s = X + (size_t)srow * NPTS + coloff;
    float4 ra = *(const float4*)s;
    float4 rb = *(const float4*)(s + 4);

    for (int c = 0; c < nchunks; ++c) {
        __syncthreads();
        float* dsh = &Xs[srow * 64 + scol];
        *(float4*)dsh       = ra;
        *(float4*)(dsh + 4) = rb;
        if (c + 1 < nchunks) {
            const float* sn = X + (size_t)((c + 1) * 32 + srow) * NPTS + coloff;
            ra = *(const float4*)sn;
            rb = *(const float4*)(sn + 4);
        }
        __syncthreads();
        const float* w0 = &W[(size_t)r0 * ldW + kOffW + c * 32];
        const float* w1 = w0 + ldW;
#pragma unroll
        for (int k = 0; k < 32; ++k) {
            float xv = Xs[k * 64 + lane];
            acc0 = fmaf(w0[k], xv, acc0);
            acc1 = fmaf(w1[k], xv, acc1);
        }
    }

    if (n < NPTS) {
        float v0 = acc0, v1 = acc1;
        if (mode == 1) { v0 = lrelu(v0); v1 = lrelu(v1); }
        else if (mode == 2) {
            v0 *= aux[r0 * NPTS + n];
            v1 *= aux[(r0 + 1) * NPTS + n];
        }
        Y[r0 * NPTS + n]       = v0;
        Y[(r0 + 1) * NPTS + n] = v1;
    }
}

// K3/K4: generic single GEMM. grid=(8, Cout/8).
__global__ __launch_bounds__(256) void gemm_single_kernel(
        const float* __restrict__ W, const float* __restrict__ Bv,
        const float* __restrict__ X, int K,
        float* __restrict__ Y, int mode, const float* __restrict__ aux) {
    __shared__ __align__(16) float Xs[32 * 64];
    const int wave = __builtin_amdgcn_readfirstlane(threadIdx.x >> 6);
    gemm_dev(W, K, 0, Bv, X, K, Y,
             blockIdx.y * 8 + wave * 2, blockIdx.x * 64, mode, aux, Xs);
}

// K5: pn3 split-K: grid=(8,20,4); part p handles k in [p*256,(p+1)*256).
__global__ __launch_bounds__(256) void gemm_splitk_kernel(
        const float* __restrict__ W, const float* __restrict__ X,
        float* __restrict__ part) {
    __shared__ __align__(16) float Xs[32 * 64];
    const int wave = __builtin_amdgcn_readfirstlane(threadIdx.x >> 6);
    const int p = blockIdx.z;
    gemm_dev(W, 1024, p * 256, nullptr,
             X + (size_t)p * 256 * NPTS, 256,
             part + (size_t)p * 80000,
             blockIdx.y * 8 + wave * 2, blockIdx.x * 64, 0, nullptr, Xs);
}

// ---------------------------------------------------------------------------
// K6: out = current_feat + mean_4( target_feat * (sum_p part + b_pn3) gathered )
// ---------------------------------------------------------------------------
__global__ __launch_bounds__(256) void final_kernel(
        const float* __restrict__ current_feat, const float* __restrict__ target_feat,
        const float* __restrict__ part, const float* __restrict__ b_pn3,
        const int* __restrict__ inds_pp, float* __restrict__ out) {
    int gid = blockIdx.x * 256 + threadIdx.x;
    if (gid >= 160 * NPTS) return;
    int ch = gid / NPTS;
    int n  = gid % NPTS;
    float bias = b_pn3[ch];
    int idxv[NPP];
#pragma unroll
    for (int j = 0; j < NPP; ++j) idxv[j] = inds_pp[n * NPP + j];
    float s = 0.f;
#pragma unroll
    for (int j = 0; j < NPP; ++j) {
        int m = ch * NPTS + idxv[j];
        float v = bias + part[m] + part[80000 + m] + part[160000 + m] + part[240000 + m];
        s += target_feat[m] * v;
    }
    out[gid] = current_feat[gid] + 0.25f * s;
}

// ---------------------------------------------------------------------------
extern "C" void kernel_launch(void* const* d_in, const int* in_sizes, int n_in,
                              void* d_out, int out_size, void* d_ws, size_t ws_size,
                              hipStream_t stream) {
    const float* img          = (const float*)d_in[0];
    const float* cloud        = (const float*)d_in[1];
    const float* img_tar      = (const float*)d_in[2];
    const float* cloud_tar    = (const float*)d_in[3];
    const float* current_feat = (const float*)d_in[4];
    const float* target_feat  = (const float*)d_in[5];
    const float* W_conv1  = (const float*)d_in[6];
    const float* b_conv1  = (const float*)d_in[7];
    const float* W_conv2  = (const float*)d_in[8];
    const float* b_conv2  = (const float*)d_in[9];
    const float* W_pconv1 = (const float*)d_in[10];
    const float* b_pconv1 = (const float*)d_in[11];
    const float* W_pconv2 = (const float*)d_in[12];
    const float* b_pconv2 = (const float*)d_in[13];
    const float* W_fc1    = (const float*)d_in[14];
    const float* b_fc1    = (const float*)d_in[15];
    const float* W_fc2    = (const float*)d_in[16];
    const float* b_fc2    = (const float*)d_in[17];
    const float* W_fuse2  = (const float*)d_in[18];
    const float* b_fuse2  = (const float*)d_in[19];
    const float* W_pn1    = (const float*)d_in[20];
    const float* b_pn1    = (const float*)d_in[21];
    const float* W_pn2    = (const float*)d_in[22];
    const float* b_pn2    = (const float*)d_in[23];
    const float* W_pn3    = (const float*)d_in[24];
    const float* b_pn3    = (const float*)d_in[25];

    // ws arena (floats); 64-float guard gaps cover GEMM staging over-reads.
    float* ws = (float*)d_ws;
    size_t off = 0;
    auto alloc = [&](size_t nfl) { float* q = ws + off; off += ((nfl + 63) & ~size_t(63)) + 64; return q; };
    int*   inds       = (int*)alloc(6000);
    int*   inds_self2 = (int*)alloc(6000);
    int*   inds_pp    = (int*)alloc(2000);
    float* w_ct       = alloc(6000);
    float* w_cc       = alloc(6000);
    float* partials   = alloc(1000);
    float* P_ct       = alloc(64000);
    float* P_c        = alloc(64000);
    float* F_it       = alloc(64000);
    float* F_ic       = alloc(64000);
    float* dcat       = alloc(256000);   // [cd;sid;id;spd] 512x500
    float* fuse_t_c   = alloc(80000);
    float* x2         = alloc(512000);
    float* pn3part    = alloc(320000);
    float* Wcomb1     = alloc(81920);    // 160x512
    float* bcomb1     = alloc(160);
    float* Wcomb2     = alloc(163840);   // 1024x160
    float* bcomb2     = alloc(1024);
    float* out        = (float*)d_out;

    // K0: weight composition (246944 outputs)
    compose_kernel<<<965, 256, 0, stream>>>(
        W_pn1, b_pn1, W_pn2, b_pn2,
        W_fc1, b_fc1, W_fc2, b_fc2, W_fuse2, b_fuse2,
        Wcomb2, bcomb2, Wcomb1, bcomb1);

    // K1: knn + featchain + softmax numerators
    knnfeat_kernel<<<407, 256, 0, stream>>>(
        cloud, cloud_tar, img, img_tar,
        W_pconv1, b_pconv1, W_pconv2, b_pconv2,
        W_conv1, b_conv1, W_conv2, b_conv2,
        inds, inds_self2, inds_pp, w_ct, w_cc, partials,
        P_ct, P_c, F_it, F_ic);

    // K2: diff + sdiff -> dcat
    diffsdiff_kernel<<<128, 256, 0, stream>>>(
        F_it, F_ic, P_ct, P_c, inds, inds_self2, w_ct, w_cc, partials, dcat);

    // K3: fuse_t_c = Wcomb1 @ dcat + bcomb1   (160,500), K=512
    gemm_single_kernel<<<dim3(8, 20), 256, 0, stream>>>(
        Wcomb1, bcomb1, dcat, 512, fuse_t_c, 0, nullptr);

    // K4: x2 = lrelu(Wcomb2 @ fuse_t_c + bcomb2)  (1024,500), K=160
    gemm_single_kernel<<<dim3(8, 128), 256, 0, stream>>>(
        Wcomb2, bcomb2, fuse_t_c, 160, x2, 1, nullptr);

    // K5: pn3 partials (split-K x4)
    gemm_splitk_kernel<<<dim3(8, 20, 4), 256, 0, stream>>>(W_pn3, x2, pn3part);

    // K6: final combine + 4-NN mean
    final_kernel<<<313, 256, 0, stream>>>(current_feat, target_feat, pn3part, b_pn3,
                                          inds_pp, out);
}

// Round 9
// 177.787 us; speedup vs baseline: 3.3996x; 1.1806x over previous
//
#include <hip/hip_runtime.h>
#include <hip/hip_bf16.h>
#include <float.h>
#include <math.h>

#define NPTS 500
#define NP12 12
#define NPP  4
#define SLOPE 0.01f

__device__ __forceinline__ float lrelu(float x) { return x > 0.f ? x : SLOPE * x; }

// ---------------------------------------------------------------------------
// prep_kernel: three independent task families in one dispatch (bid ranges):
//   [0,375)    knn: wave-per-query top-k + softmax numerators (r8-verified)
//   [375,887)  feat1: layer1 of the conv chains, thread-per-output -> mids
//   [887,1852) compose: weight composition (r8-verified)
// This kills r8's 33us tail: featchain's 32-block layer2 is gone (moved to a
// 512-block batched GEMM), and remaining low-parallelism tasks co-schedule.
// ---------------------------------------------------------------------------
__global__ __launch_bounds__(256) void prep_kernel(
        const float* __restrict__ cloud, const float* __restrict__ cloud_tar,
        const float* __restrict__ img, const float* __restrict__ img_tar,
        const float* __restrict__ Wp1, const float* __restrict__ bp1,
        const float* __restrict__ Wi1, const float* __restrict__ bi1,
        const float* __restrict__ Wpn1, const float* __restrict__ bpn1,
        const float* __restrict__ Wpn2, const float* __restrict__ bpn2,
        const float* __restrict__ Wfc1, const float* __restrict__ bfc1,
        const float* __restrict__ Wfc2, const float* __restrict__ bfc2,
        const float* __restrict__ Wf2,  const float* __restrict__ bf2,
        int* __restrict__ inds, int* __restrict__ inds_self2, int* __restrict__ inds_pp,
        float* __restrict__ w_ct, float* __restrict__ w_cc, float* __restrict__ partials,
        float* __restrict__ mids,
        float* __restrict__ Wcomb2, float* __restrict__ bcomb2,
        float* __restrict__ Wcomb1, float* __restrict__ bcomb1) {
    __shared__ __align__(16) float sm[3008];
    const int tid = threadIdx.x;
    const int bid = blockIdx.x;

    if (bid < 375) {
        // ---------------- knn task ----------------
        float* c_lds  = sm;
        float* ct_lds = sm + 1504;
        for (int i = tid; i < 1500; i += 256) {
            c_lds[i]  = cloud[i];
            ct_lds[i] = cloud_tar[i];
        }
        __syncthreads();

        const int wid  = bid * 4 + (tid >> 6);   // < 1500
        const int lane = tid & 63;
        const int prob = wid / NPTS;
        const int n    = wid % NPTS;

        const float* Q; const float* R; int k; int* out; float* w;
        if (prob == 0)      { Q = ct_lds; R = c_lds;  k = NP12; out = inds;       w = w_ct; }
        else if (prob == 1) { Q = ct_lds; R = ct_lds; k = NP12; out = inds_self2; w = w_cc; }
        else                { Q = c_lds;  R = ct_lds; k = NPP;  out = inds_pp;    w = nullptr; }

        const float qx = Q[n * 3 + 0];
        const float qy = Q[n * 3 + 1];
        const float qz = Q[n * 3 + 2];

        float d[8];
#pragma unroll
        for (int j = 0; j < 8; ++j) {
            int idx = j * 64 + lane;
            float dd = FLT_MAX;
            if (idx < NPTS) {
                float dx = qx - R[idx * 3 + 0];
                float dy = qy - R[idx * 3 + 1];
                float dz = qz - R[idx * 3 + 2];
                dd = dx * dx + dy * dy + dz * dz;
            }
            d[j] = dd;
        }

        float sum_e = 0.f;
        for (int t = 0; t < k; ++t) {
            float bv = d[0]; int bj = 0;
#pragma unroll
            for (int j = 1; j < 8; ++j) {
                if (d[j] < bv) { bv = d[j]; bj = j; }
            }
            int bidx = bj * 64 + lane;
#pragma unroll
            for (int s = 32; s >= 1; s >>= 1) {
                float ov = __shfl_xor(bv, s, 64);
                int   oi = __shfl_xor(bidx, s, 64);
                if (ov < bv || (ov == bv && oi < bidx)) { bv = ov; bidx = oi; }
            }
            if (w) {
                float e = expf(-sqrtf(bv + 1e-12f));
                sum_e += e;
                if (lane == 0) w[n * NP12 + t] = e;
            }
            if (lane == 0) out[n * k + t] = bidx;
            bool mine = (lane == (bidx & 63));
            int jj = bidx >> 6;
#pragma unroll
            for (int j = 0; j < 8; ++j) {
                if (mine && jj == j) d[j] = FLT_MAX;
            }
        }
        if (w && lane == 0) partials[wid] = sum_e;
        return;
    }

    if (bid < 887) {
        // ---------------- feat1: mids[chain][m][n] = lrelu(W1@src + b1) ----
        int gid = (bid - 375) * 256 + tid;     // < 131072; 128000 valid
        if (gid >= 128000) return;
        const int chain = gid / 32000;
        const int rem   = gid % 32000;
        const int m     = rem / NPTS;
        const int n     = rem % NPTS;

        float acc;
        if (chain < 2) {
            const float* src = chain == 0 ? cloud_tar : cloud;
            acc = bp1[m];
#pragma unroll
            for (int i = 0; i < 3; ++i)
                acc = fmaf(Wp1[m * 3 + i], src[n * 3 + i], acc);
        } else {
            const float* src = chain == 2 ? img_tar : img;
            acc = bi1[m];
#pragma unroll 8
            for (int i = 0; i < 32; ++i)
                acc = fmaf(Wi1[m * 32 + i], src[i * NPTS + n], acc);
        }
        mids[gid] = lrelu(acc);
        return;
    }

    // ---------------- compose task ----------------
    int e = (bid - 887) * 256 + tid;
    if (e < 163840) {                       // Wcomb2 = Wpn2 @ Wpn1
        int o = e / 160, j = e % 160;
        float acc = 0.f;
        for (int k = 0; k < 256; ++k)
            acc = fmaf(Wpn2[o * 256 + k], Wpn1[k * 160 + j], acc);
        Wcomb2[e] = acc;
        return;
    }
    e -= 163840;
    if (e < 81920) {                        // Wcomb1 = [Wf2L@Wfc2 | Wf2R@Wfc1]
        int o = e / 512, c = e % 512;
        float acc = 0.f;
        if (c < 256) {
            for (int m = 0; m < 64; ++m)
                acc = fmaf(Wf2[o * 128 + m], Wfc2[m * 256 + c], acc);
        } else {
            int cc = c - 256;
            for (int m = 0; m < 64; ++m)
                acc = fmaf(Wf2[o * 128 + 64 + m], Wfc1[m * 256 + cc], acc);
        }
        Wcomb1[o * 512 + c] = acc;
        return;
    }
    e -= 81920;
    if (e < 1024) {                         // bcomb2
        float acc = bpn2[e];
        for (int k = 0; k < 256; ++k)
            acc = fmaf(Wpn2[e * 256 + k], bpn1[k], acc);
        bcomb2[e] = acc;
        return;
    }
    e -= 1024;
    if (e < 160) {                          // bcomb1
        float acc = bf2[e];
        for (int m = 0; m < 64; ++m) {
            acc = fmaf(Wf2[e * 128 + m],      bfc2[m], acc);
            acc = fmaf(Wf2[e * 128 + 64 + m], bfc1[m], acc);
        }
        bcomb1[e] = acc;
    }
}

// ---------------------------------------------------------------------------
// GEMM core (verified r4/r8): Y[r,n] = bias + sum_k W[r*ldW+kOffW+k]*X[k,n].
// wave -> 2 rows x 64 cols; K chunked by 32 in LDS; register double-buffer.
// No lambdas (clang crash, r3). Over-reads <=12 floats past last row end:
// ws guard gaps cover it.
// ---------------------------------------------------------------------------
__device__ __forceinline__ void gemm_dev(
        const float* __restrict__ W, int ldW, int kOffW,
        const float* __restrict__ Bv,
        const float* __restrict__ X, int K,
        float* __restrict__ Y, int r0, int col0,
        int mode, const float* __restrict__ aux, float* Xs) {
    const int tid  = threadIdx.x;
    const int lane = tid & 63;
    const int n    = col0 + lane;
    const int srow = tid >> 3;
    const int scol = (tid & 7) * 8;
    const int coloff = col0 + scol;

    float acc0 = Bv ? Bv[r0]     : 0.f;
    float acc1 = Bv ? Bv[r0 + 1] : 0.f;

    const int nchunks = K >> 5;

    const float* s = X + (size_t)srow * NPTS + coloff;
    float4 ra = *(const float4*)s;
    float4 rb = *(const float4*)(s + 4);

    for (int c = 0; c < nchunks; ++c) {
        __syncthreads();
        float* dsh = &Xs[srow * 64 + scol];
        *(float4*)dsh       = ra;
        *(float4*)(dsh + 4) = rb;
        if (c + 1 < nchunks) {
            const float* sn = X + (size_t)((c + 1) * 32 + srow) * NPTS + coloff;
            ra = *(const float4*)sn;
            rb = *(const float4*)(sn + 4);
        }
        __syncthreads();
        const float* w0 = &W[(size_t)r0 * ldW + kOffW + c * 32];
        const float* w1 = w0 + ldW;
#pragma unroll
        for (int k = 0; k < 32; ++k) {
            float xv = Xs[k * 64 + lane];
            acc0 = fmaf(w0[k], xv, acc0);
            acc1 = fmaf(w1[k], xv, acc1);
        }
    }

    if (n < NPTS) {
        float v0 = acc0, v1 = acc1;
        if (mode == 1) { v0 = lrelu(v0); v1 = lrelu(v1); }
        else if (mode == 2) {
            v0 *= aux[r0 * NPTS + n];
            v1 *= aux[(r0 + 1) * NPTS + n];
        }
        Y[r0 * NPTS + n]       = v0;
        Y[(r0 + 1) * NPTS + n] = v1;
    }
}

// ---------------------------------------------------------------------------
// feat2: layer 2 of the conv chains as a batched GEMM. grid=(8,16,4).
// chain z: dst = W2(128x64) @ mids[z] + b2  (P_ct, P_c, F_it, F_ic).
// ---------------------------------------------------------------------------
__global__ __launch_bounds__(256) void feat2_kernel(
        const float* __restrict__ Wp2, const float* __restrict__ bp2,
        const float* __restrict__ Wi2, const float* __restrict__ bi2,
        const float* __restrict__ mids,
        float* __restrict__ P_ct, float* __restrict__ P_c,
        float* __restrict__ F_it, float* __restrict__ F_ic) {
    __shared__ __align__(16) float Xs[32 * 64];
    const int wave  = __builtin_amdgcn_readfirstlane(threadIdx.x >> 6);
    const int chain = blockIdx.z;
    const float* W  = chain < 2 ? Wp2 : Wi2;
    const float* Bv = chain < 2 ? bp2 : bi2;
    float* dst = chain == 0 ? P_ct : chain == 1 ? P_c : chain == 2 ? F_it : F_ic;
    gemm_dev(W, 64, 0, Bv, mids + (size_t)chain * 32000, 64, dst,
             blockIdx.y * 8 + wave * 2, blockIdx.x * 64, 0, nullptr, Xs);
}

// ---------------------------------------------------------------------------
// diffsdiff: diff + sdiff fused, one channel per block (128 blocks).
// Writes into dcat ([cd; sid; id; spd], 512x500) consumed by gemmA.
// ---------------------------------------------------------------------------
__global__ __launch_bounds__(256) void diffsdiff_kernel(
        const float* __restrict__ F_it, const float* __restrict__ F_ic,
        const float* __restrict__ P_ct, const float* __restrict__ P_c,
        const int* __restrict__ inds, const int* __restrict__ inds_self2,
        const float* __restrict__ w_ct, const float* __restrict__ w_cc,
        const float* __restrict__ partials,
        float* __restrict__ dcat) {
    __shared__ __align__(16) float sm[2056];
    float* sFic = sm;
    float* sPc  = sm + 512;
    float* sID  = sm + 1024;
    float* sCD  = sm + 1536;
    float* red  = sm + 2048;   // 8 floats
    const int tid = threadIdx.x;
    const int ch  = blockIdx.x;

    float l0 = 0.f, l1 = 0.f;
    for (int i = tid; i < 500; i += 256) {
        l0 += partials[i];
        l1 += partials[500 + i];
    }
#pragma unroll
    for (int s = 32; s >= 1; s >>= 1) {
        l0 += __shfl_xor(l0, s, 64);
        l1 += __shfl_xor(l1, s, 64);
    }
    if ((tid & 63) == 0) {
        red[(tid >> 6) * 2]     = l0;
        red[(tid >> 6) * 2 + 1] = l1;
    }
    for (int i = tid; i < 500; i += 256) {
        sFic[i] = F_ic[ch * NPTS + i];
        sPc[i]  = P_c[ch * NPTS + i];
    }
    __syncthreads();
    const float inv0 = 1.f / (red[0] + red[2] + red[4] + red[6]);
    const float inv1 = 1.f / (red[1] + red[3] + red[5] + red[7]);

    float* cd_row  = dcat + (size_t)ch * 500;            // rows   0..127
    float* sid_row = dcat + (size_t)(128 + ch) * 500;    // rows 128..255
    float* id_row  = dcat + (size_t)(256 + ch) * 500;    // rows 256..383
    float* spd_row = dcat + (size_t)(384 + ch) * 500;    // rows 384..511

    for (int n = tid; n < 500; n += 256) {
        float maxI = -FLT_MAX, maxP = -FLT_MAX;
#pragma unroll
        for (int j = 0; j < NP12; ++j) {
            int idx  = inds[n * NP12 + j];
            float wv = w_ct[n * NP12 + j] * inv0;
            maxI = fmaxf(maxI, sFic[idx] * wv);
            maxP = fmaxf(maxP, sPc[idx] * wv);
        }
        float idv = F_it[ch * NPTS + n] - maxI;
        float cdv = P_ct[ch * NPTS + n] - maxP;
        id_row[n] = idv;
        cd_row[n] = cdv;
        sID[n] = idv;
        sCD[n] = cdv;
    }
    __syncthreads();
    for (int n = tid; n < 500; n += 256) {
        float maxP = -FLT_MAX, maxI = -FLT_MAX;
#pragma unroll
        for (int j = 0; j < NP12; ++j) {
            int idx  = inds_self2[n * NP12 + j];
            float wv = w_cc[n * NP12 + j] * inv1;
            maxP = fmaxf(maxP, sCD[idx] * wv);
            maxI = fmaxf(maxI, sID[idx] * wv);
        }
        spd_row[n] = maxP;
        sid_row[n] = maxI;
    }
}

// generic single GEMM. grid=(8, Cout/8).
__global__ __launch_bounds__(256) void gemm_single_kernel(
        const float* __restrict__ W, const float* __restrict__ Bv,
        const float* __restrict__ X, int K,
        float* __restrict__ Y, int mode, const float* __restrict__ aux) {
    __shared__ __align__(16) float Xs[32 * 64];
    const int wave = __builtin_amdgcn_readfirstlane(threadIdx.x >> 6);
    gemm_dev(W, K, 0, Bv, X, K, Y,
             blockIdx.y * 8 + wave * 2, blockIdx.x * 64, mode, aux, Xs);
}

// pn3 split-K: grid=(8,20,4); part p handles k in [p*256,(p+1)*256).
__global__ __launch_bounds__(256) void gemm_splitk_kernel(
        const float* __restrict__ W, const float* __restrict__ X,
        float* __restrict__ part) {
    __shared__ __align__(16) float Xs[32 * 64];
    const int wave = __builtin_amdgcn_readfirstlane(threadIdx.x >> 6);
    const int p = blockIdx.z;
    gemm_dev(W, 1024, p * 256, nullptr,
             X + (size_t)p * 256 * NPTS, 256,
             part + (size_t)p * 80000,
             blockIdx.y * 8 + wave * 2, blockIdx.x * 64, 0, nullptr, Xs);
}

// ---------------------------------------------------------------------------
// final: out = current_feat + mean_4( target_feat * (sum_p part + b_pn3) )
// ---------------------------------------------------------------------------
__global__ __launch_bounds__(256) void final_kernel(
        const float* __restrict__ current_feat, const float* __restrict__ target_feat,
        const float* __restrict__ part, const float* __restrict__ b_pn3,
        const int* __restrict__ inds_pp, float* __restrict__ out) {
    int gid = blockIdx.x * 256 + threadIdx.x;
    if (gid >= 160 * NPTS) return;
    int ch = gid / NPTS;
    int n  = gid % NPTS;
    float bias = b_pn3[ch];
    int idxv[NPP];
#pragma unroll
    for (int j = 0; j < NPP; ++j) idxv[j] = inds_pp[n * NPP + j];
    float s = 0.f;
#pragma unroll
    for (int j = 0; j < NPP; ++j) {
        int m = ch * NPTS + idxv[j];
        float v = bias + part[m] + part[80000 + m] + part[160000 + m] + part[240000 + m];
        s += target_feat[m] * v;
    }
    out[gid] = current_feat[gid] + 0.25f * s;
}

// ---------------------------------------------------------------------------
extern "C" void kernel_launch(void* const* d_in, const int* in_sizes, int n_in,
                              void* d_out, int out_size, void* d_ws, size_t ws_size,
                              hipStream_t stream) {
    const float* img          = (const float*)d_in[0];
    const float* cloud        = (const float*)d_in[1];
    const float* img_tar      = (const float*)d_in[2];
    const float* cloud_tar    = (const float*)d_in[3];
    const float* current_feat = (const float*)d_in[4];
    const float* target_feat  = (const float*)d_in[5];
    const float* W_conv1  = (const float*)d_in[6];
    const float* b_conv1  = (const float*)d_in[7];
    const float* W_conv2  = (const float*)d_in[8];
    const float* b_conv2  = (const float*)d_in[9];
    const float* W_pconv1 = (const float*)d_in[10];
    const float* b_pconv1 = (const float*)d_in[11];
    const float* W_pconv2 = (const float*)d_in[12];
    const float* b_pconv2 = (const float*)d_in[13];
    const float* W_fc1    = (const float*)d_in[14];
    const float* b_fc1    = (const float*)d_in[15];
    const float* W_fc2    = (const float*)d_in[16];
    const float* b_fc2    = (const float*)d_in[17];
    const float* W_fuse2  = (const float*)d_in[18];
    const float* b_fuse2  = (const float*)d_in[19];
    const float* W_pn1    = (const float*)d_in[20];
    const float* b_pn1    = (const float*)d_in[21];
    const float* W_pn2    = (const float*)d_in[22];
    const float* b_pn2    = (const float*)d_in[23];
    const float* W_pn3    = (const float*)d_in[24];
    const float* b_pn3    = (const float*)d_in[25];

    // ws arena (floats); 64-float guard gaps cover GEMM staging over-reads.
    float* ws = (float*)d_ws;
    size_t off = 0;
    auto alloc = [&](size_t nfl) { float* q = ws + off; off += ((nfl + 63) & ~size_t(63)) + 64; return q; };
    int*   inds       = (int*)alloc(6000);
    int*   inds_self2 = (int*)alloc(6000);
    int*   inds_pp    = (int*)alloc(2000);
    float* w_ct       = alloc(6000);
    float* w_cc       = alloc(6000);
    float* partials   = alloc(1000);
    float* mids       = alloc(128000);   // [4][64][500] layer-1 outputs
    float* P_ct       = alloc(64000);
    float* P_c        = alloc(64000);
    float* F_it       = alloc(64000);
    float* F_ic       = alloc(64000);
    float* dcat       = alloc(256000);   // [cd;sid;id;spd] 512x500
    float* fuse_t_c   = alloc(80000);
    float* x2         = alloc(512000);
    float* pn3part    = alloc(320000);
    float* Wcomb1     = alloc(81920);    // 160x512
    float* bcomb1     = alloc(160);
    float* Wcomb2     = alloc(163840);   // 1024x160
    float* bcomb2     = alloc(1024);
    float* out        = (float*)d_out;

    // K1: knn + feat1 + compose (all independent), 1852 blocks
    prep_kernel<<<1852, 256, 0, stream>>>(
        cloud, cloud_tar, img, img_tar,
        W_pconv1, b_pconv1, W_conv1, b_conv1,
        W_pn1, b_pn1, W_pn2, b_pn2,
        W_fc1, b_fc1, W_fc2, b_fc2, W_fuse2, b_fuse2,
        inds, inds_self2, inds_pp, w_ct, w_cc, partials,
        mids, Wcomb2, bcomb2, Wcomb1, bcomb1);

    // K2: layer-2 batched GEMM -> P_ct, P_c, F_it, F_ic
    feat2_kernel<<<dim3(8, 16, 4), 256, 0, stream>>>(
        W_pconv2, b_pconv2, W_conv2, b_conv2, mids, P_ct, P_c, F_it, F_ic);

    // K3: diff + sdiff -> dcat
    diffsdiff_kernel<<<128, 256, 0, stream>>>(
        F_it, F_ic, P_ct, P_c, inds, inds_self2, w_ct, w_cc, partials, dcat);

    // K4: fuse_t_c = Wcomb1 @ dcat + bcomb1   (160,500), K=512
    gemm_single_kernel<<<dim3(8, 20), 256, 0, stream>>>(
        Wcomb1, bcomb1, dcat, 512, fuse_t_c, 0, nullptr);

    // K5: x2 = lrelu(Wcomb2 @ fuse_t_c + bcomb2)  (1024,500), K=160
    gemm_single_kernel<<<dim3(8, 128), 256, 0, stream>>>(
        Wcomb2, bcomb2, fuse_t_c, 160, x2, 1, nullptr);

    // K6: pn3 partials (split-K x4)
    gemm_splitk_kernel<<<dim3(8, 20, 4), 256, 0, stream>>>(W_pn3, x2, pn3part);

    // K7: final combine + 4-NN mean
    final_kernel<<<313, 256, 0, stream>>>(current_feat, target_feat, pn3part, b_pn3,
                                          inds_pp, out);
}

// Round 10
// 163.645 us; speedup vs baseline: 3.6934x; 1.0864x over previous
//
#include <hip/hip_runtime.h>
#include <hip/hip_bf16.h>
#include <float.h>
#include <math.h>

#define NPTS 500
#define NP12 12
#define NPP  4
#define SLOPE 0.01f

__device__ __forceinline__ float lrelu(float x) { return x > 0.f ? x : SLOPE * x; }

// ---------------------------------------------------------------------------
// prep_kernel: three independent task families in one dispatch (bid ranges):
//   [0,375)     knn: wave-per-query top-k + softmax numerators (r8-verified)
//   [375,503)   featchain: BOTH conv layers, self-contained per block.
//               f = bid-375: chain=f>>5, rowg=(f&31)>>3, colb=f&7.
//               Block recomputes the full 64x64 mid tile for its 64 cols
//               (x4 redundancy across rowgroups — trivial), then 32 rows of
//               layer 2. 128 light blocks hide under compose; r8's 32-block
//               33us tail is gone and so are the feat2 dispatch + mids.
//   [503,1468)  compose: weight composition (r8-verified)
// ---------------------------------------------------------------------------
__global__ __launch_bounds__(256) void prep_kernel(
        const float* __restrict__ cloud, const float* __restrict__ cloud_tar,
        const float* __restrict__ img, const float* __restrict__ img_tar,
        const float* __restrict__ Wp1, const float* __restrict__ bp1,
        const float* __restrict__ Wp2, const float* __restrict__ bp2,
        const float* __restrict__ Wi1, const float* __restrict__ bi1,
        const float* __restrict__ Wi2, const float* __restrict__ bi2,
        const float* __restrict__ Wpn1, const float* __restrict__ bpn1,
        const float* __restrict__ Wpn2, const float* __restrict__ bpn2,
        const float* __restrict__ Wfc1, const float* __restrict__ bfc1,
        const float* __restrict__ Wfc2, const float* __restrict__ bfc2,
        const float* __restrict__ Wf2,  const float* __restrict__ bf2,
        int* __restrict__ inds, int* __restrict__ inds_self2, int* __restrict__ inds_pp,
        float* __restrict__ w_ct, float* __restrict__ w_cc, float* __restrict__ partials,
        float* __restrict__ P_ct, float* __restrict__ P_c,
        float* __restrict__ F_it, float* __restrict__ F_ic,
        float* __restrict__ Wcomb2, float* __restrict__ bcomb2,
        float* __restrict__ Wcomb1, float* __restrict__ bcomb1) {
    __shared__ __align__(16) float sm[6144];
    const int tid = threadIdx.x;
    const int bid = blockIdx.x;

    if (bid < 375) {
        // ---------------- knn task ----------------
        float* c_lds  = sm;
        float* ct_lds = sm + 1504;
        for (int i = tid; i < 1500; i += 256) {
            c_lds[i]  = cloud[i];
            ct_lds[i] = cloud_tar[i];
        }
        __syncthreads();

        const int wid  = bid * 4 + (tid >> 6);   // < 1500
        const int lane = tid & 63;
        const int prob = wid / NPTS;
        const int n    = wid % NPTS;

        const float* Q; const float* R; int k; int* out; float* w;
        if (prob == 0)      { Q = ct_lds; R = c_lds;  k = NP12; out = inds;       w = w_ct; }
        else if (prob == 1) { Q = ct_lds; R = ct_lds; k = NP12; out = inds_self2; w = w_cc; }
        else                { Q = c_lds;  R = ct_lds; k = NPP;  out = inds_pp;    w = nullptr; }

        const float qx = Q[n * 3 + 0];
        const float qy = Q[n * 3 + 1];
        const float qz = Q[n * 3 + 2];

        float d[8];
#pragma unroll
        for (int j = 0; j < 8; ++j) {
            int idx = j * 64 + lane;
            float dd = FLT_MAX;
            if (idx < NPTS) {
                float dx = qx - R[idx * 3 + 0];
                float dy = qy - R[idx * 3 + 1];
                float dz = qz - R[idx * 3 + 2];
                dd = dx * dx + dy * dy + dz * dz;
            }
            d[j] = dd;
        }

        float sum_e = 0.f;
        for (int t = 0; t < k; ++t) {
            float bv = d[0]; int bj = 0;
#pragma unroll
            for (int j = 1; j < 8; ++j) {
                if (d[j] < bv) { bv = d[j]; bj = j; }
            }
            int bidx = bj * 64 + lane;
#pragma unroll
            for (int s = 32; s >= 1; s >>= 1) {
                float ov = __shfl_xor(bv, s, 64);
                int   oi = __shfl_xor(bidx, s, 64);
                if (ov < bv || (ov == bv && oi < bidx)) { bv = ov; bidx = oi; }
            }
            if (w) {
                float e = expf(-sqrtf(bv + 1e-12f));
                sum_e += e;
                if (lane == 0) w[n * NP12 + t] = e;
            }
            if (lane == 0) out[n * k + t] = bidx;
            bool mine = (lane == (bidx & 63));
            int jj = bidx >> 6;
#pragma unroll
            for (int j = 0; j < 8; ++j) {
                if (mine && jj == j) d[j] = FLT_MAX;
            }
        }
        if (w && lane == 0) partials[wid] = sum_e;
        return;
    }

    if (bid < 503) {
        // ---------------- featchain task (both layers) ----------------
        const int f     = bid - 375;        // 0..127
        const int chain = f >> 5;           // 0..3
        const int sub   = f & 31;
        const int rowg  = sub >> 3;         // 0..3
        const int col0  = (sub & 7) * 64;
        float* xin = sm;                    // 32*64
        float* mid = sm + 2048;             // 64*64

        const int wave = __builtin_amdgcn_readfirstlane(tid >> 6);
        const int lane = tid & 63;

        const float *src, *W1, *B1, *W2, *B2;
        float* dst;
        int Cin; bool coord;
        switch (chain) {
            case 0: src = cloud_tar; W1 = Wp1; B1 = bp1; W2 = Wp2; B2 = bp2; dst = P_ct; Cin = 3;  coord = true;  break;
            case 1: src = cloud;     W1 = Wp1; B1 = bp1; W2 = Wp2; B2 = bp2; dst = P_c;  Cin = 3;  coord = true;  break;
            case 2: src = img_tar;   W1 = Wi1; B1 = bi1; W2 = Wi2; B2 = bi2; dst = F_it; Cin = 32; coord = false; break;
            default:src = img;       W1 = Wi1; B1 = bi1; W2 = Wi2; B2 = bi2; dst = F_ic; Cin = 32; coord = false; break;
        }

        for (int idx = tid; idx < Cin * 64; idx += 256) {
            int i = idx >> 6;
            int cl = idx & 63;
            int nn = col0 + cl;
            float v = 0.f;
            if (nn < NPTS) v = coord ? src[nn * 3 + i] : src[i * NPTS + nn];
            xin[i * 64 + cl] = v;
        }
        __syncthreads();

        {   // layer 1: full 64-row mid tile (wave -> 16 rows)
            const int m0 = wave * 16;
            float accm[16];
#pragma unroll
            for (int r = 0; r < 16; ++r) accm[r] = B1[m0 + r];
            for (int i = 0; i < Cin; ++i) {
                float xv = xin[i * 64 + lane];
#pragma unroll
                for (int r = 0; r < 16; ++r)
                    accm[r] = fmaf(W1[(m0 + r) * Cin + i], xv, accm[r]);
            }
#pragma unroll
            for (int r = 0; r < 16; ++r)
                mid[(m0 + r) * 64 + lane] = lrelu(accm[r]);
        }
        __syncthreads();

        {   // layer 2: this block's 32 rows (wave -> 8 rows)
            const int o0 = rowg * 32 + wave * 8;
            float acc[8];
#pragma unroll
            for (int r = 0; r < 8; ++r) acc[r] = B2[o0 + r];
#pragma unroll 16
            for (int m = 0; m < 64; ++m) {
                float xv = mid[m * 64 + lane];
#pragma unroll
                for (int r = 0; r < 8; ++r)
                    acc[r] = fmaf(W2[(o0 + r) * 64 + m], xv, acc[r]);
            }
            const int nn = col0 + lane;
            if (nn < NPTS) {
#pragma unroll
                for (int r = 0; r < 8; ++r)
                    dst[(o0 + r) * NPTS + nn] = acc[r];
            }
        }
        return;
    }

    // ---------------- compose task ----------------
    int e = (bid - 503) * 256 + tid;
    if (e < 163840) {                       // Wcomb2 = Wpn2 @ Wpn1
        int o = e / 160, j = e % 160;
        float acc = 0.f;
        for (int k = 0; k < 256; ++k)
            acc = fmaf(Wpn2[o * 256 + k], Wpn1[k * 160 + j], acc);
        Wcomb2[e] = acc;
        return;
    }
    e -= 163840;
    if (e < 81920) {                        // Wcomb1 = [Wf2L@Wfc2 | Wf2R@Wfc1]
        int o = e / 512, c = e % 512;
        float acc = 0.f;
        if (c < 256) {
            for (int m = 0; m < 64; ++m)
                acc = fmaf(Wf2[o * 128 + m], Wfc2[m * 256 + c], acc);
        } else {
            int cc = c - 256;
            for (int m = 0; m < 64; ++m)
                acc = fmaf(Wf2[o * 128 + 64 + m], Wfc1[m * 256 + cc], acc);
        }
        Wcomb1[o * 512 + c] = acc;
        return;
    }
    e -= 81920;
    if (e < 1024) {                         // bcomb2
        float acc = bpn2[e];
        for (int k = 0; k < 256; ++k)
            acc = fmaf(Wpn2[e * 256 + k], bpn1[k], acc);
        bcomb2[e] = acc;
        return;
    }
    e -= 1024;
    if (e < 160) {                          // bcomb1
        float acc = bf2[e];
        for (int m = 0; m < 64; ++m) {
            acc = fmaf(Wf2[e * 128 + m],      bfc2[m], acc);
            acc = fmaf(Wf2[e * 128 + 64 + m], bfc1[m], acc);
        }
        bcomb1[e] = acc;
    }
}

// ---------------------------------------------------------------------------
// diffsdiff: diff + sdiff fused, one channel per block, 512 threads (8 waves
// for 2x latency hiding of the gather passes). Writes dcat ([cd;sid;id;spd],
// 512x500) consumed by gemmA.
// ---------------------------------------------------------------------------
__global__ __launch_bounds__(512) void diffsdiff_kernel(
        const float* __restrict__ F_it, const float* __restrict__ F_ic,
        const float* __restrict__ P_ct, const float* __restrict__ P_c,
        const int* __restrict__ inds, const int* __restrict__ inds_self2,
        const float* __restrict__ w_ct, const float* __restrict__ w_cc,
        const float* __restrict__ partials,
        float* __restrict__ dcat) {
    __shared__ __align__(16) float sm[2064];
    float* sFic = sm;
    float* sPc  = sm + 512;
    float* sID  = sm + 1024;
    float* sCD  = sm + 1536;
    float* red  = sm + 2048;   // 16 floats (8 waves x 2)
    const int tid = threadIdx.x;
    const int ch  = blockIdx.x;

    float l0 = 0.f, l1 = 0.f;
    for (int i = tid; i < 500; i += 512) {
        l0 += partials[i];
        l1 += partials[500 + i];
    }
#pragma unroll
    for (int s = 32; s >= 1; s >>= 1) {
        l0 += __shfl_xor(l0, s, 64);
        l1 += __shfl_xor(l1, s, 64);
    }
    if ((tid & 63) == 0) {
        red[(tid >> 6) * 2]     = l0;
        red[(tid >> 6) * 2 + 1] = l1;
    }
    for (int i = tid; i < 500; i += 512) {
        sFic[i] = F_ic[ch * NPTS + i];
        sPc[i]  = P_c[ch * NPTS + i];
    }
    __syncthreads();
    float t0 = 0.f, t1 = 0.f;
#pragma unroll
    for (int wv = 0; wv < 8; ++wv) { t0 += red[wv * 2]; t1 += red[wv * 2 + 1]; }
    const float inv0 = 1.f / t0;
    const float inv1 = 1.f / t1;

    float* cd_row  = dcat + (size_t)ch * 500;            // rows   0..127
    float* sid_row = dcat + (size_t)(128 + ch) * 500;    // rows 128..255
    float* id_row  = dcat + (size_t)(256 + ch) * 500;    // rows 256..383
    float* spd_row = dcat + (size_t)(384 + ch) * 500;    // rows 384..511

    for (int n = tid; n < 500; n += 512) {
        float maxI = -FLT_MAX, maxP = -FLT_MAX;
#pragma unroll
        for (int j = 0; j < NP12; ++j) {
            int idx  = inds[n * NP12 + j];
            float wv = w_ct[n * NP12 + j] * inv0;
            maxI = fmaxf(maxI, sFic[idx] * wv);
            maxP = fmaxf(maxP, sPc[idx] * wv);
        }
        float idv = F_it[ch * NPTS + n] - maxI;
        float cdv = P_ct[ch * NPTS + n] - maxP;
        id_row[n] = idv;
        cd_row[n] = cdv;
        sID[n] = idv;
        sCD[n] = cdv;
    }
    __syncthreads();
    for (int n = tid; n < 500; n += 512) {
        float maxP = -FLT_MAX, maxI = -FLT_MAX;
#pragma unroll
        for (int j = 0; j < NP12; ++j) {
            int idx  = inds_self2[n * NP12 + j];
            float wv = w_cc[n * NP12 + j] * inv1;
            maxP = fmaxf(maxP, sCD[idx] * wv);
            maxI = fmaxf(maxI, sID[idx] * wv);
        }
        spd_row[n] = maxP;
        sid_row[n] = maxI;
    }
}

// ---------------------------------------------------------------------------
// GEMM core (verified r4/r8): Y[r,n] = bias + sum_k W[r*ldW+kOffW+k]*X[k,n].
// Optional Xb: stages X+Xb elementwise (sums split-K partials for free).
// wave -> 2 rows x 64 cols; K chunked by 32 in LDS; register double-buffer.
// No lambdas (clang crash, r3). Over-reads <=12 floats past last row end:
// ws guard gaps cover it.
// ---------------------------------------------------------------------------
__device__ __forceinline__ void gemm_dev(
        const float* __restrict__ W, int ldW, int kOffW,
        const float* __restrict__ Bv,
        const float* __restrict__ X, const float* __restrict__ Xb, int K,
        float* __restrict__ Y, int r0, int col0,
        int mode, const float* __restrict__ aux, float* Xs) {
    const int tid  = threadIdx.x;
    const int lane = tid & 63;
    const int n    = col0 + lane;
    const int srow = tid >> 3;
    const int scol = (tid & 7) * 8;
    const int coloff = col0 + scol;

    float acc0 = Bv ? Bv[r0]     : 0.f;
    float acc1 = Bv ? Bv[r0 + 1] : 0.f;

    const int nchunks = K >> 5;

    const float* s = X + (size_t)srow * NPTS + coloff;
    float4 ra = *(const float4*)s;
    float4 rb = *(const float4*)(s + 4);
    if (Xb) {
        const float* sb = Xb + (size_t)srow * NPTS + coloff;
        float4 ba = *(const float4*)sb;
        float4 bb = *(const float4*)(sb + 4);
        ra.x += ba.x; ra.y += ba.y; ra.z += ba.z; ra.w += ba.w;
        rb.x += bb.x; rb.y += bb.y; rb.z += bb.z; rb.w += bb.w;
    }

    for (int c = 0; c < nchunks; ++c) {
        __syncthreads();
        float* dsh = &Xs[srow * 64 + scol];
        *(float4*)dsh       = ra;
        *(float4*)(dsh + 4) = rb;
        if (c + 1 < nchunks) {
            size_t row = (size_t)((c + 1) * 32 + srow) * NPTS + coloff;
            const float* sn = X + row;
            ra = *(const float4*)sn;
            rb = *(const float4*)(sn + 4);
            if (Xb) {
                const float* sbn = Xb + row;
                float4 ba = *(const float4*)sbn;
                float4 bb = *(const float4*)(sbn + 4);
                ra.x += ba.x; ra.y += ba.y; ra.z += ba.z; ra.w += ba.w;
                rb.x += bb.x; rb.y += bb.y; rb.z += bb.z; rb.w += bb.w;
            }
        }
        __syncthreads();
        const float* w0 = &W[(size_t)r0 * ldW + kOffW + c * 32];
        const float* w1 = w0 + ldW;
#pragma unroll
        for (int k = 0; k < 32; ++k) {
            float xv = Xs[k * 64 + lane];
            acc0 = fmaf(w0[k], xv, acc0);
            acc1 = fmaf(w1[k], xv, acc1);
        }
    }

    if (n < NPTS) {
        float v0 = acc0, v1 = acc1;
        if (mode == 1) { v0 = lrelu(v0); v1 = lrelu(v1); }
        else if (mode == 2) {
            v0 *= aux[r0 * NPTS + n];
            v1 *= aux[(r0 + 1) * NPTS + n];
        }
        Y[r0 * NPTS + n]       = v0;
        Y[(r0 + 1) * NPTS + n] = v1;
    }
}

// generic single GEMM (optional Xb partial-sum input). grid=(8, Cout/8).
__global__ __launch_bounds__(256) void gemm_single_kernel(
        const float* __restrict__ W, const float* __restrict__ Bv,
        const float* __restrict__ X, const float* __restrict__ Xb, int K,
        float* __restrict__ Y, int mode, const float* __restrict__ aux) {
    __shared__ __align__(16) float Xs[32 * 64];
    const int wave = __builtin_amdgcn_readfirstlane(threadIdx.x >> 6);
    gemm_dev(W, K, 0, Bv, X, Xb, K, Y,
             blockIdx.y * 8 + wave * 2, blockIdx.x * 64, mode, aux, Xs);
}

// gemmA split-K x2: grid=(8,20,2); part p covers dcat rows [p*256,(p+1)*256).
// Bias carried by part 0 only; gemmB sums the parts while staging.
__global__ __launch_bounds__(256) void gemmA_splitk_kernel(
        const float* __restrict__ Wcomb1, const float* __restrict__ bcomb1,
        const float* __restrict__ dcat,
        float* __restrict__ part0, float* __restrict__ part1) {
    __shared__ __align__(16) float Xs[32 * 64];
    const int wave = __builtin_amdgcn_readfirstlane(threadIdx.x >> 6);
    const int p = blockIdx.z;
    gemm_dev(Wcomb1, 512, p * 256, p == 0 ? bcomb1 : (const float*)nullptr,
             dcat + (size_t)p * 256 * NPTS, nullptr, 256,
             p == 0 ? part0 : part1,
             blockIdx.y * 8 + wave * 2, blockIdx.x * 64, 0, nullptr, Xs);
}

// pn3 split-K x4: grid=(8,20,4); part p handles k in [p*256,(p+1)*256).
__global__ __launch_bounds__(256) void gemm_splitk_kernel(
        const float* __restrict__ W, const float* __restrict__ X,
        float* __restrict__ part) {
    __shared__ __align__(16) float Xs[32 * 64];
    const int wave = __builtin_amdgcn_readfirstlane(threadIdx.x >> 6);
    const int p = blockIdx.z;
    gemm_dev(W, 1024, p * 256, nullptr,
             X + (size_t)p * 256 * NPTS, nullptr, 256,
             part + (size_t)p * 80000,
             blockIdx.y * 8 + wave * 2, blockIdx.x * 64, 0, nullptr, Xs);
}

// ---------------------------------------------------------------------------
// final: out = current_feat + mean_4( target_feat * (sum_p part + b_pn3) )
// ---------------------------------------------------------------------------
__global__ __launch_bounds__(256) void final_kernel(
        const float* __restrict__ current_feat, const float* __restrict__ target_feat,
        const float* __restrict__ part, const float* __restrict__ b_pn3,
        const int* __restrict__ inds_pp, float* __restrict__ out) {
    int gid = blockIdx.x * 256 + threadIdx.x;
    if (gid >= 160 * NPTS) return;
    int ch = gid / NPTS;
    int n  = gid % NPTS;
    float bias = b_pn3[ch];
    int idxv[NPP];
#pragma unroll
    for (int j = 0; j < NPP; ++j) idxv[j] = inds_pp[n * NPP + j];
    float s = 0.f;
#pragma unroll
    for (int j = 0; j < NPP; ++j) {
        int m = ch * NPTS + idxv[j];
        float v = bias + part[m] + part[80000 + m] + part[160000 + m] + part[240000 + m];
        s += target_feat[m] * v;
    }
    out[gid] = current_feat[gid] + 0.25f * s;
}

// ---------------------------------------------------------------------------
extern "C" void kernel_launch(void* const* d_in, const int* in_sizes, int n_in,
                              void* d_out, int out_size, void* d_ws, size_t ws_size,
                              hipStream_t stream) {
    const float* img          = (const float*)d_in[0];
    const float* cloud        = (const float*)d_in[1];
    const float* img_tar      = (const float*)d_in[2];
    const float* cloud_tar    = (const float*)d_in[3];
    const float* current_feat = (const float*)d_in[4];
    const float* target_feat  = (const float*)d_in[5];
    const float* W_conv1  = (const float*)d_in[6];
    const float* b_conv1  = (const float*)d_in[7];
    const float* W_conv2  = (const float*)d_in[8];
    const float* b_conv2  = (const float*)d_in[9];
    const float* W_pconv1 = (const float*)d_in[10];
    const float* b_pconv1 = (const float*)d_in[11];
    const float* W_pconv2 = (const float*)d_in[12];
    const float* b_pconv2 = (const float*)d_in[13];
    const float* W_fc1    = (const float*)d_in[14];
    const float* b_fc1    = (const float*)d_in[15];
    const float* W_fc2    = (const float*)d_in[16];
    const float* b_fc2    = (const float*)d_in[17];
    const float* W_fuse2  = (const float*)d_in[18];
    const float* b_fuse2  = (const float*)d_in[19];
    const float* W_pn1    = (const float*)d_in[20];
    const float* b_pn1    = (const float*)d_in[21];
    const float* W_pn2    = (const float*)d_in[22];
    const float* b_pn2    = (const float*)d_in[23];
    const float* W_pn3    = (const float*)d_in[24];
    const float* b_pn3    = (const float*)d_in[25];

    // ws arena (floats); 64-float guard gaps cover GEMM staging over-reads.
    float* ws = (float*)d_ws;
    size_t off = 0;
    auto alloc = [&](size_t nfl) { float* q = ws + off; off += ((nfl + 63) & ~size_t(63)) + 64; return q; };
    int*   inds       = (int*)alloc(6000);
    int*   inds_self2 = (int*)alloc(6000);
    int*   inds_pp    = (int*)alloc(2000);
    float* w_ct       = alloc(6000);
    float* w_cc       = alloc(6000);
    float* partials   = alloc(1000);
    float* P_ct       = alloc(64000);
    float* P_c        = alloc(64000);
    float* F_it       = alloc(64000);
    float* F_ic       = alloc(64000);
    float* dcat       = alloc(256000);   // [cd;sid;id;spd] 512x500
    float* fpart0     = alloc(80000);    // gemmA split-K partials
    float* fpart1     = alloc(80000);
    float* x2         = alloc(512000);
    float* pn3part    = alloc(320000);
    float* Wcomb1     = alloc(81920);    // 160x512
    float* bcomb1     = alloc(160);
    float* Wcomb2     = alloc(163840);   // 1024x160
    float* bcomb2     = alloc(1024);
    float* out        = (float*)d_out;

    // K1: knn + featchain(both layers) + compose, 1468 blocks
    prep_kernel<<<1468, 256, 0, stream>>>(
        cloud, cloud_tar, img, img_tar,
        W_pconv1, b_pconv1, W_pconv2, b_pconv2,
        W_conv1, b_conv1, W_conv2, b_conv2,
        W_pn1, b_pn1, W_pn2, b_pn2,
        W_fc1, b_fc1, W_fc2, b_fc2, W_fuse2, b_fuse2,
        inds, inds_self2, inds_pp, w_ct, w_cc, partials,
        P_ct, P_c, F_it, F_ic,
        Wcomb2, bcomb2, Wcomb1, bcomb1);

    // K2: diff + sdiff -> dcat (512 threads/block)
    diffsdiff_kernel<<<128, 512, 0, stream>>>(
        F_it, F_ic, P_ct, P_c, inds, inds_self2, w_ct, w_cc, partials, dcat);

    // K3: fuse_t_c partials = Wcomb1 @ dcat + bcomb1 (split-K x2)
    gemmA_splitk_kernel<<<dim3(8, 20, 2), 256, 0, stream>>>(
        Wcomb1, bcomb1, dcat, fpart0, fpart1);

    // K4: x2 = lrelu(Wcomb2 @ (fpart0+fpart1) + bcomb2)  (1024,500), K=160
    gemm_single_kernel<<<dim3(8, 128), 256, 0, stream>>>(
        Wcomb2, bcomb2, fpart0, fpart1, 160, x2, 1, nullptr);

    // K5: pn3 partials (split-K x4)
    gemm_splitk_kernel<<<dim3(8, 20, 4), 256, 0, stream>>>(W_pn3, x2, pn3part);

    // K6: final combine + 4-NN mean
    final_kernel<<<313, 256, 0, stream>>>(current_feat, target_feat, pn3part, b_pn3,
                                          inds_pp, out);
}